// Round 7
// baseline (13575.322 us; speedup 1.0000x reference)
//
#include <hip/hip_runtime.h>

#define NPTS 16384
#define CH 128
#define KNN 9
#define NCAND 12
#define COUT 256

// Insert (d, idx) into an ascending (dist, idx)-lexicographic sorted top-N list.
template <int N>
__device__ __forceinline__ void insertN(float (&L)[N], int (&I)[N], float d, int idx) {
    bool pre = (d < L[N - 1]) || (d == L[N - 1] && idx < I[N - 1]);
    if (pre) {
        bool gt[N];
#pragma unroll
        for (int j = 0; j < N; ++j) gt[j] = (d < L[j]) || (d == L[j] && idx < I[j]);
#pragma unroll
        for (int j = N - 1; j >= 1; --j) {
            bool sh = gt[j - 1];
            L[j] = sh ? L[j - 1] : (gt[j] ? d : L[j]);
            I[j] = sh ? I[j - 1] : (gt[j] ? idx : I[j]);
        }
        if (gt[0]) { L[0] = d; I[0] = idx; }
    }
}

// ---------------- Kernel 1: numpy pairwise_sum replica of np.sum(x*x, -1) ----------------
// numpy loops.c.src base case (n=128 <= PW_BLOCKSIZE): products pre-rounded (separate
// multiply ufunc), then 8 scalar accumulators stride-8, 16 sequential adds each,
// combined ((r0+r1)+(r2+r3))+((r4+r5)+(r6+r7)). All via __fmul_rn/__fadd_rn.
// DO NOT TOUCH: this exact rounding order is what makes selection match the reference.
__global__ __launch_bounds__(256) void sqnp_kernel(const float* __restrict__ x,
                                                   float* __restrict__ sq) {
    const int i = blockIdx.x * 256 + threadIdx.x;
    const float4* row4 = (const float4*)(x + (size_t)i * CH);
    float r[8];
    {
        float4 a = row4[0], b = row4[1];
        r[0] = __fmul_rn(a.x, a.x); r[1] = __fmul_rn(a.y, a.y);
        r[2] = __fmul_rn(a.z, a.z); r[3] = __fmul_rn(a.w, a.w);
        r[4] = __fmul_rn(b.x, b.x); r[5] = __fmul_rn(b.y, b.y);
        r[6] = __fmul_rn(b.z, b.z); r[7] = __fmul_rn(b.w, b.w);
    }
#pragma unroll
    for (int g = 1; g < 16; ++g) {
        float4 a = row4[2 * g], b = row4[2 * g + 1];
        r[0] = __fadd_rn(r[0], __fmul_rn(a.x, a.x));
        r[1] = __fadd_rn(r[1], __fmul_rn(a.y, a.y));
        r[2] = __fadd_rn(r[2], __fmul_rn(a.z, a.z));
        r[3] = __fadd_rn(r[3], __fmul_rn(a.w, a.w));
        r[4] = __fadd_rn(r[4], __fmul_rn(b.x, b.x));
        r[5] = __fadd_rn(r[5], __fmul_rn(b.y, b.y));
        r[6] = __fadd_rn(r[6], __fmul_rn(b.z, b.z));
        r[7] = __fadd_rn(r[7], __fmul_rn(b.w, b.w));
    }
    float t0 = __fadd_rn(__fadd_rn(r[0], r[1]), __fadd_rn(r[2], r[3]));
    float t1 = __fadd_rn(__fadd_rn(r[4], r[5]), __fadd_rn(r[6], r[7]));
    sq[i] = __fadd_rn(t0, t1);
}

// ---------------- Kernel 2: fused fp32 distance-GEMM + top-12 candidates ----------------
// launch_bounds(256, 1): VGPR cap 256 — the top-12 lists (96 VGPRs) MUST stay
// register-resident. The (256,2) variant capped at 128 VGPR and spilled the lists
// to scratch: 5.4 GB HBM writes, VALUBusy 7%, 13.4 ms. (round-6 counters)
__global__ __launch_bounds__(256, 1) void knn_kernel(const float* __restrict__ x,
                                                     const float* __restrict__ sq,
                                                     int* __restrict__ cand) {
    __shared__ float Xq[64 * 128];
    __shared__ float Xc[2 * 64 * 64];
    const int t = threadIdx.x;
    const int txl = t >> 4;
    const int ty = t & 15;
    const int row0 = blockIdx.x * 64;
    const int qsw = (txl & 3) << 4;
    const int csw = ty << 2;

    {
        const float4* xg = (const float4*)(x + (size_t)row0 * CH);
#pragma unroll
        for (int it = 0; it < 8; ++it) {
            int fg = t + it * 256;
            int r = fg >> 5;
            int c4 = fg & 31;
            float4 v = xg[fg];
            *(float4*)&Xq[r * 128 + 4 * (c4 ^ ((r & 3) << 2))] = v;
        }
    }

    float sqr[4];
#pragma unroll
    for (int s = 0; s < 4; ++s) sqr[s] = sq[row0 + txl + 16 * s];

    float ld[4][NCAND];
    int li[4][NCAND];
#pragma unroll
    for (int s = 0; s < 4; ++s)
#pragma unroll
        for (int j = 0; j < NCAND; ++j) { ld[s][j] = __builtin_inff(); li[s][j] = 0x7fffffff; }

    const float* qp = Xq + txl * 128;
    const float* cp = Xc + ty * 64;

    for (int ct = 0; ct < NPTS; ct += 64) {
        const float4* xg = (const float4*)(x + (size_t)ct * CH);
#pragma unroll
        for (int it = 0; it < 8; ++it) {
            int fg = t + it * 256;
            int r = fg >> 5;
            int c4 = fg & 31;
            int h = c4 >> 4;
            int j = c4 & 15;
            float4 v = xg[fg];
            *(float4*)&Xc[h * 4096 + r * 64 + 4 * (j ^ (r & 15))] = v;
        }
        float sqc[4];
#pragma unroll
        for (int u = 0; u < 4; ++u) sqc[u] = sq[ct + ty + 16 * u];
        __syncthreads();

        float acc[4][4];
#pragma unroll
        for (int s = 0; s < 4; ++s)
#pragma unroll
            for (int u = 0; u < 4; ++u) acc[s][u] = 0.f;

#pragma unroll 4
        for (int k0 = 0; k0 < CH; k0 += 4) {
            float4 a[4], b[4];
            const int qo = k0 ^ qsw;
            const int co = ((k0 >> 6) * 4096) + ((k0 & 63) ^ csw);
#pragma unroll
            for (int s = 0; s < 4; ++s) a[s] = *(const float4*)(qp + s * 2048 + qo);
#pragma unroll
            for (int u = 0; u < 4; ++u) b[u] = *(const float4*)(cp + u * 1024 + co);
#pragma unroll
            for (int s = 0; s < 4; ++s)
#pragma unroll
                for (int u = 0; u < 4; ++u) {
                    acc[s][u] += a[s].x * b[u].x;
                    acc[s][u] += a[s].y * b[u].y;
                    acc[s][u] += a[s].z * b[u].z;
                    acc[s][u] += a[s].w * b[u].w;
                }
        }
        __syncthreads();

#pragma unroll
        for (int s = 0; s < 4; ++s) {
            const int rg = row0 + txl + 16 * s;
#pragma unroll
            for (int u = 0; u < 4; ++u) {
                const int cg = ct + ty + 16 * u;
                if (cg != rg) {
                    float d = sqr[s] + sqc[u] - 2.f * acc[s][u];
                    insertN<NCAND>(ld[s], li[s], d, cg);
                }
            }
        }
    }

#pragma unroll
    for (int s = 0; s < 4; ++s) {
#pragma unroll
        for (int st = 0; st < 4; ++st) {
            const int step = 1 << st;
            float od[NCAND];
            int oi[NCAND];
#pragma unroll
            for (int j = 0; j < NCAND; ++j) {
                od[j] = __shfl_xor(ld[s][j], step, 16);
                oi[j] = __shfl_xor(li[s][j], step, 16);
            }
#pragma unroll
            for (int j = 0; j < NCAND; ++j) insertN<NCAND>(ld[s], li[s], od[j], oi[j]);
        }
        if (ty == 0) {
            const int rg = row0 + txl + 16 * s;
#pragma unroll
            for (int j = 0; j < NCAND; ++j) cand[rg * NCAND + j] = li[s][j];
        }
    }
}

// ---------------- Kernel 2.5: numpy-fp32-replica re-rank of 12 candidates ----------------
// dot: BLAS sgemm per-element rounding = ONE accumulator, sequential ascending-k FMA.
// sq : numpy pairwise_sum replica (sqnp_kernel).
// d  : fl( fl(sq_i + sq_j) - fl(2*dot) )  -- numpy's elementwise combine.
// DO NOT TOUCH the rounding order — verified exact vs reference (round 6, absmax 0.0).
__global__ __launch_bounds__(256) void refine_np_kernel(const float* __restrict__ x,
                                                        const float* __restrict__ sq,
                                                        const int* __restrict__ cand,
                                                        int* __restrict__ nbr) {
    const int i = blockIdx.x * 256 + threadIdx.x;
    const float4* X4 = (const float4*)x;
    int ci[NCAND];
#pragma unroll
    for (int m = 0; m < NCAND; ++m) ci[m] = cand[i * NCAND + m];
    float dot[NCAND];
#pragma unroll
    for (int m = 0; m < NCAND; ++m) dot[m] = 0.f;
#pragma unroll 4
    for (int c4 = 0; c4 < 32; ++c4) {
        float4 xv = X4[(size_t)i * 32 + c4];
#pragma unroll
        for (int m = 0; m < NCAND; ++m) {
            float4 nv = X4[(size_t)ci[m] * 32 + c4];
            float a = dot[m];
            a = __builtin_fmaf(xv.x, nv.x, a);
            a = __builtin_fmaf(xv.y, nv.y, a);
            a = __builtin_fmaf(xv.z, nv.z, a);
            a = __builtin_fmaf(xv.w, nv.w, a);
            dot[m] = a;
        }
    }
    const float sqi = sq[i];
    float d[NCAND];
#pragma unroll
    for (int m = 0; m < NCAND; ++m) {
        float s = __fadd_rn(sqi, sq[ci[m]]);
        d[m] = __fsub_rn(s, __fmul_rn(2.0f, dot[m]));
    }

    unsigned used = 0;
#pragma unroll
    for (int s = 0; s < KNN; ++s) {
        float bd = __builtin_inff();
        int bi = 0x7fffffff, bm = 0;
#pragma unroll
        for (int m = 0; m < NCAND; ++m) {
            bool ok = !((used >> m) & 1);
            bool better = ok && ((d[m] < bd) || (d[m] == bd && ci[m] < bi));
            bd = better ? d[m] : bd;
            bi = better ? ci[m] : bi;
            bm = better ? m : bm;
        }
        used |= (1u << bm);
        nbr[i * KNN + s] = bi;
    }
}

// ---------------- Kernel 3: rel-pos add + max-relative + concat-GEMM ----------------
__global__ __launch_bounds__(256, 2) void out_kernel(const float* __restrict__ x,
                                                     const float* __restrict__ tab,
                                                     const float* __restrict__ W,
                                                     const float* __restrict__ bias,
                                                     const int* __restrict__ nbr,
                                                     float* __restrict__ out) {
    __shared__ float cat[32][260];
    const int t = threadIdx.x;
    const int row0 = blockIdx.x * 32;
    {
        const int row = t >> 3;
        const int q = t & 7;
        const int i = row0 + row;
        const int rel_i = (i >> 7) - (i & 127) + 127;
        int nb[KNN], reln[KNN];
#pragma unroll
        for (int j = 0; j < KNN; ++j) {
            nb[j] = nbr[i * KNN + j];
            reln[j] = (nb[j] >> 7) - (nb[j] & 127) + 127;
        }
        const float4* X4 = (const float4*)x;
        const float4* T4 = (const float4*)tab;
#pragma unroll
        for (int cc = 0; cc < 4; ++cc) {
            const int c4 = q * 4 + cc;
            float4 xv = X4[i * 32 + c4];
            float4 tv = T4[rel_i * 32 + c4];
            float4 xi;
            xi.x = xv.x + tv.x; xi.y = xv.y + tv.y; xi.z = xv.z + tv.z; xi.w = xv.w + tv.w;
            const float ninf = -__builtin_inff();
            float4 mx = {ninf, ninf, ninf, ninf};
#pragma unroll
            for (int j = 0; j < KNN; ++j) {
                float4 nv = X4[nb[j] * 32 + c4];
                float4 ntv = T4[reln[j] * 32 + c4];
                mx.x = fmaxf(mx.x, nv.x + ntv.x - xi.x);
                mx.y = fmaxf(mx.y, nv.y + ntv.y - xi.y);
                mx.z = fmaxf(mx.z, nv.z + ntv.z - xi.z);
                mx.w = fmaxf(mx.w, nv.w + ntv.w - xi.w);
            }
            *(float4*)&cat[row][c4 * 4] = xi;
            *(float4*)&cat[row][CH + c4 * 4] = mx;
        }
    }
    __syncthreads();

    float acc[32];
    const float bo = bias[t];
#pragma unroll
    for (int i = 0; i < 32; ++i) acc[i] = bo;
#pragma unroll 2
    for (int c0 = 0; c0 < 2 * CH; c0 += 4) {
        const float w0 = W[(c0 + 0) * COUT + t];
        const float w1 = W[(c0 + 1) * COUT + t];
        const float w2 = W[(c0 + 2) * COUT + t];
        const float w3 = W[(c0 + 3) * COUT + t];
#pragma unroll
        for (int i = 0; i < 32; ++i) {
            const float4 cv = *(const float4*)&cat[i][c0];
            acc[i] = fmaf(cv.x, w0, acc[i]);
            acc[i] = fmaf(cv.y, w1, acc[i]);
            acc[i] = fmaf(cv.z, w2, acc[i]);
            acc[i] = fmaf(cv.w, w3, acc[i]);
        }
    }
#pragma unroll
    for (int i = 0; i < 32; ++i) out[(size_t)(row0 + i) * COUT + t] = acc[i];
}

extern "C" void kernel_launch(void* const* d_in, const int* in_sizes, int n_in,
                              void* d_out, int out_size, void* d_ws, size_t ws_size,
                              hipStream_t stream) {
    (void)in_sizes; (void)n_in; (void)out_size; (void)ws_size;
    const float* x = (const float*)d_in[0];
    const float* tab = (const float*)d_in[1];
    const float* W = (const float*)d_in[2];
    const float* b = (const float*)d_in[3];
    float* out = (float*)d_out;

    char* ws = (char*)d_ws;
    float* sq = (float*)ws;                  // N floats
    int* cand = (int*)(sq + NPTS);           // N*12 ints
    int* nbr = cand + (size_t)NPTS * NCAND;  // N*9 ints

    sqnp_kernel<<<NPTS / 256, 256, 0, stream>>>(x, sq);
    knn_kernel<<<NPTS / 64, 256, 0, stream>>>(x, sq, cand);
    refine_np_kernel<<<NPTS / 256, 256, 0, stream>>>(x, sq, cand, nbr);
    out_kernel<<<NPTS / 32, 256, 0, stream>>>(x, tab, W, b, nbr, out);
}

// Round 8
// 2779.641 us; speedup vs baseline: 4.8838x; 4.8838x over previous
//
#include <hip/hip_runtime.h>

#define NPTS 16384
#define CH 128
#define KNN 9
#define NCAND 12
#define COUT 256

// ---- Register-guaranteed top-12 list: named scalars only (no arrays!). ----
// LLVM SROA runs before loop unrolling, so loop-indexed private arrays stay in
// scratch (round 6/7: 5.4 GB scratch writes, VALUBusy 7%). Named members are
// constant-offset accesses from IR-gen -> always promoted to VGPRs.
struct TopL {
    float l0,l1,l2,l3,l4,l5,l6,l7,l8,l9,la,lb;
    int   m0,m1,m2,m3,m4,m5,m6,m7,m8,m9,ma,mb;
};

__device__ __forceinline__ bool lexlt(float d, int g, float L, int M) {
    return d < L || (d == L && g < M);
}

// Branch-guarded, select-based sorted insert (ascending (d, idx)-lex).
__device__ __forceinline__ void ins12(TopL& T, float d, int g) {
    if (!lexlt(d, g, T.lb, T.mb)) return;
    bool b0 = lexlt(d,g,T.l0,T.m0);
    bool b1 = lexlt(d,g,T.l1,T.m1);
    bool b2 = lexlt(d,g,T.l2,T.m2);
    bool b3 = lexlt(d,g,T.l3,T.m3);
    bool b4 = lexlt(d,g,T.l4,T.m4);
    bool b5 = lexlt(d,g,T.l5,T.m5);
    bool b6 = lexlt(d,g,T.l6,T.m6);
    bool b7 = lexlt(d,g,T.l7,T.m7);
    bool b8 = lexlt(d,g,T.l8,T.m8);
    bool b9 = lexlt(d,g,T.l9,T.m9);
    bool ba = lexlt(d,g,T.la,T.ma);
    T.lb = ba ? T.la : d;               T.mb = ba ? T.ma : g;
    T.la = b9 ? T.l9 : (ba ? d : T.la); T.ma = b9 ? T.m9 : (ba ? g : T.ma);
    T.l9 = b8 ? T.l8 : (b9 ? d : T.l9); T.m9 = b8 ? T.m8 : (b9 ? g : T.m9);
    T.l8 = b7 ? T.l7 : (b8 ? d : T.l8); T.m8 = b7 ? T.m7 : (b8 ? g : T.m8);
    T.l7 = b6 ? T.l6 : (b7 ? d : T.l7); T.m7 = b6 ? T.m6 : (b7 ? g : T.m7);
    T.l6 = b5 ? T.l5 : (b6 ? d : T.l6); T.m6 = b5 ? T.m5 : (b6 ? g : T.m6);
    T.l5 = b4 ? T.l4 : (b5 ? d : T.l5); T.m5 = b4 ? T.m4 : (b5 ? g : T.m5);
    T.l4 = b3 ? T.l3 : (b4 ? d : T.l4); T.m4 = b3 ? T.m3 : (b4 ? g : T.m4);
    T.l3 = b2 ? T.l2 : (b3 ? d : T.l3); T.m3 = b2 ? T.m2 : (b3 ? g : T.m3);
    T.l2 = b1 ? T.l1 : (b2 ? d : T.l2); T.m2 = b1 ? T.m1 : (b2 ? g : T.m2);
    T.l1 = b0 ? T.l0 : (b1 ? d : T.l1); T.m1 = b0 ? T.m0 : (b1 ? g : T.m1);
    T.l0 = b0 ? d : T.l0;               T.m0 = b0 ? g : T.m0;
}

__device__ __forceinline__ void merge_shfl(TopL& T, int mask) {
    TopL o;
    o.l0=__shfl_xor(T.l0,mask); o.m0=__shfl_xor(T.m0,mask);
    o.l1=__shfl_xor(T.l1,mask); o.m1=__shfl_xor(T.m1,mask);
    o.l2=__shfl_xor(T.l2,mask); o.m2=__shfl_xor(T.m2,mask);
    o.l3=__shfl_xor(T.l3,mask); o.m3=__shfl_xor(T.m3,mask);
    o.l4=__shfl_xor(T.l4,mask); o.m4=__shfl_xor(T.m4,mask);
    o.l5=__shfl_xor(T.l5,mask); o.m5=__shfl_xor(T.m5,mask);
    o.l6=__shfl_xor(T.l6,mask); o.m6=__shfl_xor(T.m6,mask);
    o.l7=__shfl_xor(T.l7,mask); o.m7=__shfl_xor(T.m7,mask);
    o.l8=__shfl_xor(T.l8,mask); o.m8=__shfl_xor(T.m8,mask);
    o.l9=__shfl_xor(T.l9,mask); o.m9=__shfl_xor(T.m9,mask);
    o.la=__shfl_xor(T.la,mask); o.ma=__shfl_xor(T.ma,mask);
    o.lb=__shfl_xor(T.lb,mask); o.mb=__shfl_xor(T.mb,mask);
    ins12(T,o.l0,o.m0); ins12(T,o.l1,o.m1); ins12(T,o.l2,o.m2);
    ins12(T,o.l3,o.m3); ins12(T,o.l4,o.m4); ins12(T,o.l5,o.m5);
    ins12(T,o.l6,o.m6); ins12(T,o.l7,o.m7); ins12(T,o.l8,o.m8);
    ins12(T,o.l9,o.m9); ins12(T,o.la,o.ma); ins12(T,o.lb,o.mb);
}

// ---------------- Kernel 1: numpy pairwise_sum replica of np.sum(x*x, -1) ----------------
// DO NOT TOUCH: this exact rounding order is what makes selection match the
// reference bit-for-bit (round 6, absmax 0.0).
__global__ __launch_bounds__(256) void sqnp_kernel(const float* __restrict__ x,
                                                   float* __restrict__ sq) {
    const int i = blockIdx.x * 256 + threadIdx.x;
    const float4* row4 = (const float4*)(x + (size_t)i * CH);
    float r[8];
    {
        float4 a = row4[0], b = row4[1];
        r[0] = __fmul_rn(a.x, a.x); r[1] = __fmul_rn(a.y, a.y);
        r[2] = __fmul_rn(a.z, a.z); r[3] = __fmul_rn(a.w, a.w);
        r[4] = __fmul_rn(b.x, b.x); r[5] = __fmul_rn(b.y, b.y);
        r[6] = __fmul_rn(b.z, b.z); r[7] = __fmul_rn(b.w, b.w);
    }
#pragma unroll
    for (int g = 1; g < 16; ++g) {
        float4 a = row4[2 * g], b = row4[2 * g + 1];
        r[0] = __fadd_rn(r[0], __fmul_rn(a.x, a.x));
        r[1] = __fadd_rn(r[1], __fmul_rn(a.y, a.y));
        r[2] = __fadd_rn(r[2], __fmul_rn(a.z, a.z));
        r[3] = __fadd_rn(r[3], __fmul_rn(a.w, a.w));
        r[4] = __fadd_rn(r[4], __fmul_rn(b.x, b.x));
        r[5] = __fadd_rn(r[5], __fmul_rn(b.y, b.y));
        r[6] = __fadd_rn(r[6], __fmul_rn(b.z, b.z));
        r[7] = __fadd_rn(r[7], __fmul_rn(b.w, b.w));
    }
    float t0 = __fadd_rn(__fadd_rn(r[0], r[1]), __fadd_rn(r[2], r[3]));
    float t1 = __fadd_rn(__fadd_rn(r[4], r[5]), __fadd_rn(r[6], r[7]));
    sq[i] = __fadd_rn(t0, t1);
}

// ---------------- Kernel 2: fused fp32 distance-GEMM + top-12 candidates ----------------
// GEMM phase: 4x4 micro-tile per thread (txl,ty), distances -> Dist LDS (XOR-row
// swizzle). Selection phase: thread t scans row t>>2, cols (t&3)*16..+15, with a
// named-scalar TopL (register-guaranteed); 2-step shfl merge across the 4 threads.
// LDS: 32K Xq + 32K Xc + 16K Dist = 80 KiB -> 2 blocks/CU.
__global__ __launch_bounds__(256, 2) void knn_kernel(const float* __restrict__ x,
                                                     const float* __restrict__ sq,
                                                     int* __restrict__ cand) {
    __shared__ float Xq[64 * 128];
    __shared__ float Xc[2 * 64 * 64];
    __shared__ float Dist[64 * 64];
    const int t = threadIdx.x;
    const int txl = t >> 4;
    const int ty = t & 15;
    const int row0 = blockIdx.x * 64;
    const int qsw = (txl & 3) << 4;
    const int csw = ty << 2;

    {
        const float4* xg = (const float4*)(x + (size_t)row0 * CH);
#pragma unroll
        for (int it = 0; it < 8; ++it) {
            int fg = t + it * 256;
            int r = fg >> 5;
            int c4 = fg & 31;
            float4 v = xg[fg];
            *(float4*)&Xq[r * 128 + 4 * (c4 ^ ((r & 3) << 2))] = v;
        }
    }

    float sqr[4];
#pragma unroll
    for (int s = 0; s < 4; ++s) sqr[s] = sq[row0 + txl + 16 * s];

    TopL T;
    T.l0=T.l1=T.l2=T.l3=T.l4=T.l5=T.l6=T.l7=T.l8=T.l9=T.la=T.lb = __builtin_inff();
    T.m0=T.m1=T.m2=T.m3=T.m4=T.m5=T.m6=T.m7=T.m8=T.m9=T.ma=T.mb = 0x7fffffff;

    const int srow = t >> 2;       // selection-phase row (0..63)
    const int sq4 = t & 3;         // selection-phase column quarter
    const int srowg = row0 + srow;

    const float* qp = Xq + txl * 128;
    const float* cp = Xc + ty * 64;

    for (int ct = 0; ct < NPTS; ct += 64) {
        const float4* xg = (const float4*)(x + (size_t)ct * CH);
#pragma unroll
        for (int it = 0; it < 8; ++it) {
            int fg = t + it * 256;
            int r = fg >> 5;
            int c4 = fg & 31;
            int h = c4 >> 4;
            int j = c4 & 15;
            float4 v = xg[fg];
            *(float4*)&Xc[h * 4096 + r * 64 + 4 * (j ^ (r & 15))] = v;
        }
        float sqc[4];
#pragma unroll
        for (int u = 0; u < 4; ++u) sqc[u] = sq[ct + ty + 16 * u];
        __syncthreads();

        float acc[4][4];
#pragma unroll
        for (int s = 0; s < 4; ++s)
#pragma unroll
            for (int u = 0; u < 4; ++u) acc[s][u] = 0.f;

#pragma unroll 4
        for (int k0 = 0; k0 < CH; k0 += 4) {
            float4 a[4], b[4];
            const int qo = k0 ^ qsw;
            const int co = ((k0 >> 6) * 4096) + ((k0 & 63) ^ csw);
#pragma unroll
            for (int s = 0; s < 4; ++s) a[s] = *(const float4*)(qp + s * 2048 + qo);
#pragma unroll
            for (int u = 0; u < 4; ++u) b[u] = *(const float4*)(cp + u * 1024 + co);
#pragma unroll
            for (int s = 0; s < 4; ++s)
#pragma unroll
                for (int u = 0; u < 4; ++u) {
                    acc[s][u] += a[s].x * b[u].x;
                    acc[s][u] += a[s].y * b[u].y;
                    acc[s][u] += a[s].z * b[u].z;
                    acc[s][u] += a[s].w * b[u].w;
                }
        }

        // distances -> Dist LDS, physical col = col ^ row (reads 2-way free)
#pragma unroll
        for (int s = 0; s < 4; ++s) {
            const int row = txl + 16 * s;
#pragma unroll
            for (int u = 0; u < 4; ++u) {
                const int col = ty + 16 * u;
                Dist[row * 64 + (col ^ row)] = sqr[s] + sqc[u] - 2.f * acc[s][u];
            }
        }
        __syncthreads();

        // selection scan: 16 candidates from this tile for row srow
#pragma unroll
        for (int k = 0; k < 16; ++k) {
            const int col = sq4 * 16 + k;
            const float d = Dist[srow * 64 + (col ^ srow)];
            const int cg = ct + col;
            if (cg != srowg) ins12(T, d, cg);
        }
    }

    // merge the 4 partial lists per row (lanes t^1, t^2 share srow)
    merge_shfl(T, 1);
    merge_shfl(T, 2);

    if (sq4 == 0) {
        int* cp_out = cand + (size_t)srowg * NCAND;
        cp_out[0]=T.m0; cp_out[1]=T.m1; cp_out[2]=T.m2;  cp_out[3]=T.m3;
        cp_out[4]=T.m4; cp_out[5]=T.m5; cp_out[6]=T.m6;  cp_out[7]=T.m7;
        cp_out[8]=T.m8; cp_out[9]=T.m9; cp_out[10]=T.ma; cp_out[11]=T.mb;
    }
}

// ---------------- Kernel 2.5: numpy-fp32-replica re-rank of 12 candidates ----------------
// dot: BLAS sgemm per-element rounding = ONE accumulator, sequential ascending-k FMA.
// d  : fl( fl(sq_i + sq_j) - fl(2*dot) ).
// DO NOT TOUCH the rounding order — verified exact vs reference (round 6, absmax 0.0).
__global__ __launch_bounds__(256) void refine_np_kernel(const float* __restrict__ x,
                                                        const float* __restrict__ sq,
                                                        const int* __restrict__ cand,
                                                        int* __restrict__ nbr) {
    const int i = blockIdx.x * 256 + threadIdx.x;
    const float4* X4 = (const float4*)x;
    int ci[NCAND];
#pragma unroll
    for (int m = 0; m < NCAND; ++m) ci[m] = cand[i * NCAND + m];
    float dot[NCAND];
#pragma unroll
    for (int m = 0; m < NCAND; ++m) dot[m] = 0.f;
#pragma unroll 4
    for (int c4 = 0; c4 < 32; ++c4) {
        float4 xv = X4[(size_t)i * 32 + c4];
#pragma unroll
        for (int m = 0; m < NCAND; ++m) {
            float4 nv = X4[(size_t)ci[m] * 32 + c4];
            float a = dot[m];
            a = __builtin_fmaf(xv.x, nv.x, a);
            a = __builtin_fmaf(xv.y, nv.y, a);
            a = __builtin_fmaf(xv.z, nv.z, a);
            a = __builtin_fmaf(xv.w, nv.w, a);
            dot[m] = a;
        }
    }
    const float sqi = sq[i];
    float d[NCAND];
#pragma unroll
    for (int m = 0; m < NCAND; ++m) {
        float s = __fadd_rn(sqi, sq[ci[m]]);
        d[m] = __fsub_rn(s, __fmul_rn(2.0f, dot[m]));
    }

    unsigned used = 0;
#pragma unroll
    for (int s = 0; s < KNN; ++s) {
        float bd = __builtin_inff();
        int bi = 0x7fffffff, bm = 0;
#pragma unroll
        for (int m = 0; m < NCAND; ++m) {
            bool ok = !((used >> m) & 1);
            bool better = ok && ((d[m] < bd) || (d[m] == bd && ci[m] < bi));
            bd = better ? d[m] : bd;
            bi = better ? ci[m] : bi;
            bm = better ? m : bm;
        }
        used |= (1u << bm);
        nbr[i * KNN + s] = bi;
    }
}

// ---------------- Kernel 3: rel-pos add + max-relative + concat-GEMM ----------------
__global__ __launch_bounds__(256, 2) void out_kernel(const float* __restrict__ x,
                                                     const float* __restrict__ tab,
                                                     const float* __restrict__ W,
                                                     const float* __restrict__ bias,
                                                     const int* __restrict__ nbr,
                                                     float* __restrict__ out) {
    __shared__ float cat[32][260];
    const int t = threadIdx.x;
    const int row0 = blockIdx.x * 32;
    {
        const int row = t >> 3;
        const int q = t & 7;
        const int i = row0 + row;
        const int rel_i = (i >> 7) - (i & 127) + 127;
        int nb[KNN], reln[KNN];
#pragma unroll
        for (int j = 0; j < KNN; ++j) {
            nb[j] = nbr[i * KNN + j];
            reln[j] = (nb[j] >> 7) - (nb[j] & 127) + 127;
        }
        const float4* X4 = (const float4*)x;
        const float4* T4 = (const float4*)tab;
#pragma unroll
        for (int cc = 0; cc < 4; ++cc) {
            const int c4 = q * 4 + cc;
            float4 xv = X4[i * 32 + c4];
            float4 tv = T4[rel_i * 32 + c4];
            float4 xi;
            xi.x = xv.x + tv.x; xi.y = xv.y + tv.y; xi.z = xv.z + tv.z; xi.w = xv.w + tv.w;
            const float ninf = -__builtin_inff();
            float4 mx = {ninf, ninf, ninf, ninf};
#pragma unroll
            for (int j = 0; j < KNN; ++j) {
                float4 nv = X4[nb[j] * 32 + c4];
                float4 ntv = T4[reln[j] * 32 + c4];
                mx.x = fmaxf(mx.x, nv.x + ntv.x - xi.x);
                mx.y = fmaxf(mx.y, nv.y + ntv.y - xi.y);
                mx.z = fmaxf(mx.z, nv.z + ntv.z - xi.z);
                mx.w = fmaxf(mx.w, nv.w + ntv.w - xi.w);
            }
            *(float4*)&cat[row][c4 * 4] = xi;
            *(float4*)&cat[row][CH + c4 * 4] = mx;
        }
    }
    __syncthreads();

    float acc[32];
    const float bo = bias[t];
#pragma unroll
    for (int i = 0; i < 32; ++i) acc[i] = bo;
#pragma unroll 2
    for (int c0 = 0; c0 < 2 * CH; c0 += 4) {
        const float w0 = W[(c0 + 0) * COUT + t];
        const float w1 = W[(c0 + 1) * COUT + t];
        const float w2 = W[(c0 + 2) * COUT + t];
        const float w3 = W[(c0 + 3) * COUT + t];
#pragma unroll
        for (int i = 0; i < 32; ++i) {
            const float4 cv = *(const float4*)&cat[i][c0];
            acc[i] = fmaf(cv.x, w0, acc[i]);
            acc[i] = fmaf(cv.y, w1, acc[i]);
            acc[i] = fmaf(cv.z, w2, acc[i]);
            acc[i] = fmaf(cv.w, w3, acc[i]);
        }
    }
#pragma unroll
    for (int i = 0; i < 32; ++i) out[(size_t)(row0 + i) * COUT + t] = acc[i];
}

extern "C" void kernel_launch(void* const* d_in, const int* in_sizes, int n_in,
                              void* d_out, int out_size, void* d_ws, size_t ws_size,
                              hipStream_t stream) {
    (void)in_sizes; (void)n_in; (void)out_size; (void)ws_size;
    const float* x = (const float*)d_in[0];
    const float* tab = (const float*)d_in[1];
    const float* W = (const float*)d_in[2];
    const float* b = (const float*)d_in[3];
    float* out = (float*)d_out;

    char* ws = (char*)d_ws;
    float* sq = (float*)ws;                  // N floats
    int* cand = (int*)(sq + NPTS);           // N*12 ints
    int* nbr = cand + (size_t)NPTS * NCAND;  // N*9 ints

    sqnp_kernel<<<NPTS / 256, 256, 0, stream>>>(x, sq);
    knn_kernel<<<NPTS / 64, 256, 0, stream>>>(x, sq, cand);
    refine_np_kernel<<<NPTS / 256, 256, 0, stream>>>(x, sq, cand, nbr);
    out_kernel<<<NPTS / 32, 256, 0, stream>>>(x, tab, W, b, nbr, out);
}

// Round 11
// 1977.912 us; speedup vs baseline: 6.8635x; 1.4053x over previous
//
#include <hip/hip_runtime.h>

#define NPTS 16384
#define CH 128
#define KNN 9
#define NCAND 12          // per column-half
#define NHALF 2           // column splits
#define COUT 256

// Workspace budget: ws_size is unknown but >= 1.375 MiB (round 8 passed) and
// < 2.125 MiB (round 10 corrupted harness memory -> post-timing divergence).
// Indices < 16384 -> pack cand/nbr as uint16: 64K + 768K + 288K = 1.09 MiB.

// ---- Register-guaranteed top-k lists: named scalars only (no arrays!). ----
// LLVM SROA runs before loop unrolling, so loop-indexed private arrays stay in
// scratch (round 6/7: 5.4 GB scratch writes, VALUBusy 7%). Named members are
// constant-offset accesses from IR-gen -> always promoted to VGPRs.
struct TopL {
    float l0,l1,l2,l3,l4,l5,l6,l7,l8,l9,la,lb;
    int   m0,m1,m2,m3,m4,m5,m6,m7,m8,m9,ma,mb;
};
struct Top9 {
    float l0,l1,l2,l3,l4,l5,l6,l7,l8;
    int   m0,m1,m2,m3,m4,m5,m6,m7,m8;
};

__device__ __forceinline__ bool lexlt(float d, int g, float L, int M) {
    return d < L || (d == L && g < M);
}

__device__ __forceinline__ void ins12(TopL& T, float d, int g) {
    if (!lexlt(d, g, T.lb, T.mb)) return;
    bool b0 = lexlt(d,g,T.l0,T.m0);
    bool b1 = lexlt(d,g,T.l1,T.m1);
    bool b2 = lexlt(d,g,T.l2,T.m2);
    bool b3 = lexlt(d,g,T.l3,T.m3);
    bool b4 = lexlt(d,g,T.l4,T.m4);
    bool b5 = lexlt(d,g,T.l5,T.m5);
    bool b6 = lexlt(d,g,T.l6,T.m6);
    bool b7 = lexlt(d,g,T.l7,T.m7);
    bool b8 = lexlt(d,g,T.l8,T.m8);
    bool b9 = lexlt(d,g,T.l9,T.m9);
    bool ba = lexlt(d,g,T.la,T.ma);
    T.lb = ba ? T.la : d;               T.mb = ba ? T.ma : g;
    T.la = b9 ? T.l9 : (ba ? d : T.la); T.ma = b9 ? T.m9 : (ba ? g : T.ma);
    T.l9 = b8 ? T.l8 : (b9 ? d : T.l9); T.m9 = b8 ? T.m8 : (b9 ? g : T.m9);
    T.l8 = b7 ? T.l7 : (b8 ? d : T.l8); T.m8 = b7 ? T.m7 : (b8 ? g : T.m8);
    T.l7 = b6 ? T.l6 : (b7 ? d : T.l7); T.m7 = b6 ? T.m6 : (b7 ? g : T.m7);
    T.l6 = b5 ? T.l5 : (b6 ? d : T.l6); T.m6 = b5 ? T.m5 : (b6 ? g : T.m6);
    T.l5 = b4 ? T.l4 : (b5 ? d : T.l5); T.m5 = b4 ? T.m4 : (b5 ? g : T.m5);
    T.l4 = b3 ? T.l3 : (b4 ? d : T.l4); T.m4 = b3 ? T.m3 : (b4 ? g : T.m4);
    T.l3 = b2 ? T.l2 : (b3 ? d : T.l3); T.m3 = b2 ? T.m2 : (b3 ? g : T.m3);
    T.l2 = b1 ? T.l1 : (b2 ? d : T.l2); T.m2 = b1 ? T.m1 : (b2 ? g : T.m2);
    T.l1 = b0 ? T.l0 : (b1 ? d : T.l1); T.m1 = b0 ? T.m0 : (b1 ? g : T.m1);
    T.l0 = b0 ? d : T.l0;               T.m0 = b0 ? g : T.m0;
}

__device__ __forceinline__ void ins9(Top9& T, float d, int g) {
    if (!lexlt(d, g, T.l8, T.m8)) return;
    bool b0 = lexlt(d,g,T.l0,T.m0);
    bool b1 = lexlt(d,g,T.l1,T.m1);
    bool b2 = lexlt(d,g,T.l2,T.m2);
    bool b3 = lexlt(d,g,T.l3,T.m3);
    bool b4 = lexlt(d,g,T.l4,T.m4);
    bool b5 = lexlt(d,g,T.l5,T.m5);
    bool b6 = lexlt(d,g,T.l6,T.m6);
    bool b7 = lexlt(d,g,T.l7,T.m7);
    T.l8 = b7 ? T.l7 : d;               T.m8 = b7 ? T.m7 : g;
    T.l7 = b6 ? T.l6 : (b7 ? d : T.l7); T.m7 = b6 ? T.m6 : (b7 ? g : T.m7);
    T.l6 = b5 ? T.l5 : (b6 ? d : T.l6); T.m6 = b5 ? T.m5 : (b6 ? g : T.m6);
    T.l5 = b4 ? T.l4 : (b5 ? d : T.l5); T.m5 = b4 ? T.m4 : (b5 ? g : T.m5);
    T.l4 = b3 ? T.l3 : (b4 ? d : T.l4); T.m4 = b3 ? T.m3 : (b4 ? g : T.m4);
    T.l3 = b2 ? T.l2 : (b3 ? d : T.l3); T.m3 = b2 ? T.m2 : (b3 ? g : T.m3);
    T.l2 = b1 ? T.l1 : (b2 ? d : T.l2); T.m2 = b1 ? T.m1 : (b2 ? g : T.m2);
    T.l1 = b0 ? T.l0 : (b1 ? d : T.l1); T.m1 = b0 ? T.m0 : (b1 ? g : T.m1);
    T.l0 = b0 ? d : T.l0;               T.m0 = b0 ? g : T.m0;
}

__device__ __forceinline__ void merge_shfl(TopL& T, int mask) {
    TopL o;
    o.l0=__shfl_xor(T.l0,mask); o.m0=__shfl_xor(T.m0,mask);
    o.l1=__shfl_xor(T.l1,mask); o.m1=__shfl_xor(T.m1,mask);
    o.l2=__shfl_xor(T.l2,mask); o.m2=__shfl_xor(T.m2,mask);
    o.l3=__shfl_xor(T.l3,mask); o.m3=__shfl_xor(T.m3,mask);
    o.l4=__shfl_xor(T.l4,mask); o.m4=__shfl_xor(T.m4,mask);
    o.l5=__shfl_xor(T.l5,mask); o.m5=__shfl_xor(T.m5,mask);
    o.l6=__shfl_xor(T.l6,mask); o.m6=__shfl_xor(T.m6,mask);
    o.l7=__shfl_xor(T.l7,mask); o.m7=__shfl_xor(T.m7,mask);
    o.l8=__shfl_xor(T.l8,mask); o.m8=__shfl_xor(T.m8,mask);
    o.l9=__shfl_xor(T.l9,mask); o.m9=__shfl_xor(T.m9,mask);
    o.la=__shfl_xor(T.la,mask); o.ma=__shfl_xor(T.ma,mask);
    o.lb=__shfl_xor(T.lb,mask); o.mb=__shfl_xor(T.mb,mask);
    ins12(T,o.l0,o.m0); ins12(T,o.l1,o.m1); ins12(T,o.l2,o.m2);
    ins12(T,o.l3,o.m3); ins12(T,o.l4,o.m4); ins12(T,o.l5,o.m5);
    ins12(T,o.l6,o.m6); ins12(T,o.l7,o.m7); ins12(T,o.l8,o.m8);
    ins12(T,o.l9,o.m9); ins12(T,o.la,o.ma); ins12(T,o.lb,o.mb);
}

// ---------------- Kernel 1: numpy pairwise_sum replica of np.sum(x*x, -1) ----------------
// DO NOT TOUCH: this exact rounding order makes selection match the reference
// bit-for-bit (round 6, absmax 0.0).
__global__ __launch_bounds__(256) void sqnp_kernel(const float* __restrict__ x,
                                                   float* __restrict__ sq) {
    const int i = blockIdx.x * 256 + threadIdx.x;
    const float4* row4 = (const float4*)(x + (size_t)i * CH);
    float r[8];
    {
        float4 a = row4[0], b = row4[1];
        r[0] = __fmul_rn(a.x, a.x); r[1] = __fmul_rn(a.y, a.y);
        r[2] = __fmul_rn(a.z, a.z); r[3] = __fmul_rn(a.w, a.w);
        r[4] = __fmul_rn(b.x, b.x); r[5] = __fmul_rn(b.y, b.y);
        r[6] = __fmul_rn(b.z, b.z); r[7] = __fmul_rn(b.w, b.w);
    }
#pragma unroll
    for (int g = 1; g < 16; ++g) {
        float4 a = row4[2 * g], b = row4[2 * g + 1];
        r[0] = __fadd_rn(r[0], __fmul_rn(a.x, a.x));
        r[1] = __fadd_rn(r[1], __fmul_rn(a.y, a.y));
        r[2] = __fadd_rn(r[2], __fmul_rn(a.z, a.z));
        r[3] = __fadd_rn(r[3], __fmul_rn(a.w, a.w));
        r[4] = __fadd_rn(r[4], __fmul_rn(b.x, b.x));
        r[5] = __fadd_rn(r[5], __fmul_rn(b.y, b.y));
        r[6] = __fadd_rn(r[6], __fmul_rn(b.z, b.z));
        r[7] = __fadd_rn(r[7], __fmul_rn(b.w, b.w));
    }
    float t0 = __fadd_rn(__fadd_rn(r[0], r[1]), __fadd_rn(r[2], r[3]));
    float t1 = __fadd_rn(__fadd_rn(r[4], r[5]), __fadd_rn(r[6], r[7]));
    sq[i] = __fadd_rn(t0, t1);
}

// ---------------- Kernel 2: fused fp32 distance-GEMM + per-half top-12 ----------------
// Grid (NPTS/64, NHALF): blockIdx.x = 64-row tile, blockIdx.y = column half.
// Column split -> 2 blocks/CU resident (LDS 80 KiB); round-10 timing confirmed
// the ~2x knn speedup (total 2780 -> 1833 us) before the ws overrun was found.
__global__ __launch_bounds__(256, 2) void knn_kernel(const float* __restrict__ x,
                                                     const float* __restrict__ sq,
                                                     unsigned short* __restrict__ cand) {
    __shared__ float Xq[64 * 128];
    __shared__ float Xc[2 * 64 * 64];
    __shared__ float Dist[64 * 64];
    const int t = threadIdx.x;
    const int txl = t >> 4;
    const int ty = t & 15;
    const int row0 = blockIdx.x * 64;
    const int half = blockIdx.y;
    const int ctbeg = half * (NPTS / NHALF);
    const int ctend = ctbeg + NPTS / NHALF;
    const int qsw = (txl & 3) << 4;
    const int csw = ty << 2;

    {
        const float4* xg = (const float4*)(x + (size_t)row0 * CH);
#pragma unroll
        for (int it = 0; it < 8; ++it) {
            int fg = t + it * 256;
            int r = fg >> 5;
            int c4 = fg & 31;
            float4 v = xg[fg];
            *(float4*)&Xq[r * 128 + 4 * (c4 ^ ((r & 3) << 2))] = v;
        }
    }

    float sqr[4];
#pragma unroll
    for (int s = 0; s < 4; ++s) sqr[s] = sq[row0 + txl + 16 * s];

    TopL T;
    T.l0=T.l1=T.l2=T.l3=T.l4=T.l5=T.l6=T.l7=T.l8=T.l9=T.la=T.lb = __builtin_inff();
    T.m0=T.m1=T.m2=T.m3=T.m4=T.m5=T.m6=T.m7=T.m8=T.m9=T.ma=T.mb = 0x7fffffff;

    const int srow = t >> 2;       // selection-phase row (0..63)
    const int sq4 = t & 3;         // selection-phase column quarter
    const int srowg = row0 + srow;

    const float* qp = Xq + txl * 128;
    const float* cp = Xc + ty * 64;

    for (int ct = ctbeg; ct < ctend; ct += 64) {
        const float4* xg = (const float4*)(x + (size_t)ct * CH);
#pragma unroll
        for (int it = 0; it < 8; ++it) {
            int fg = t + it * 256;
            int r = fg >> 5;
            int c4 = fg & 31;
            int h = c4 >> 4;
            int j = c4 & 15;
            float4 v = xg[fg];
            *(float4*)&Xc[h * 4096 + r * 64 + 4 * (j ^ (r & 15))] = v;
        }
        float sqc[4];
#pragma unroll
        for (int u = 0; u < 4; ++u) sqc[u] = sq[ct + ty + 16 * u];
        __syncthreads();

        float acc[4][4];
#pragma unroll
        for (int s = 0; s < 4; ++s)
#pragma unroll
            for (int u = 0; u < 4; ++u) acc[s][u] = 0.f;

#pragma unroll 4
        for (int k0 = 0; k0 < CH; k0 += 4) {
            float4 a[4], b[4];
            const int qo = k0 ^ qsw;
            const int co = ((k0 >> 6) * 4096) + ((k0 & 63) ^ csw);
#pragma unroll
            for (int s = 0; s < 4; ++s) a[s] = *(const float4*)(qp + s * 2048 + qo);
#pragma unroll
            for (int u = 0; u < 4; ++u) b[u] = *(const float4*)(cp + u * 1024 + co);
#pragma unroll
            for (int s = 0; s < 4; ++s)
#pragma unroll
                for (int u = 0; u < 4; ++u) {
                    acc[s][u] += a[s].x * b[u].x;
                    acc[s][u] += a[s].y * b[u].y;
                    acc[s][u] += a[s].z * b[u].z;
                    acc[s][u] += a[s].w * b[u].w;
                }
        }

        // distances -> Dist LDS, physical col = col ^ row
#pragma unroll
        for (int s = 0; s < 4; ++s) {
            const int row = txl + 16 * s;
#pragma unroll
            for (int u = 0; u < 4; ++u) {
                const int col = ty + 16 * u;
                Dist[row * 64 + (col ^ row)] = sqr[s] + sqc[u] - 2.f * acc[s][u];
            }
        }
        __syncthreads();

        // selection scan: 16 candidates from this tile for row srow
#pragma unroll
        for (int k = 0; k < 16; ++k) {
            const int col = sq4 * 16 + k;
            const float d = Dist[srow * 64 + (col ^ srow)];
            const int cg = ct + col;
            if (cg != srowg) ins12(T, d, cg);
        }
    }

    // merge the 4 partial lists per row (lanes t^1, t^2 share srow)
    merge_shfl(T, 1);
    merge_shfl(T, 2);

    if (sq4 == 0) {
        unsigned short* cp_out = cand + (size_t)srowg * (NHALF * NCAND) + half * NCAND;
        cp_out[0]=(unsigned short)T.m0; cp_out[1]=(unsigned short)T.m1;
        cp_out[2]=(unsigned short)T.m2; cp_out[3]=(unsigned short)T.m3;
        cp_out[4]=(unsigned short)T.m4; cp_out[5]=(unsigned short)T.m5;
        cp_out[6]=(unsigned short)T.m6; cp_out[7]=(unsigned short)T.m7;
        cp_out[8]=(unsigned short)T.m8; cp_out[9]=(unsigned short)T.m9;
        cp_out[10]=(unsigned short)T.ma; cp_out[11]=(unsigned short)T.mb;
    }
}

// ---------------- Kernel 2.5: numpy-fp32-replica re-rank of 24 candidates ----------------
// dot: BLAS sgemm per-element rounding = ONE accumulator, sequential ascending-k FMA.
// d  : fl( fl(sq_i + sq_j) - fl(2*dot) ).
// DO NOT TOUCH the rounding order — verified exact vs reference (round 6, absmax 0.0).
__global__ __launch_bounds__(256) void refine_np_kernel(const float* __restrict__ x,
                                                        const float* __restrict__ sq,
                                                        const unsigned short* __restrict__ cand,
                                                        unsigned short* __restrict__ nbr) {
    const int i = blockIdx.x * 256 + threadIdx.x;
    const float4* X4 = (const float4*)x;
    const float sqi = sq[i];

    Top9 T;
    T.l0=T.l1=T.l2=T.l3=T.l4=T.l5=T.l6=T.l7=T.l8 = __builtin_inff();
    T.m0=T.m1=T.m2=T.m3=T.m4=T.m5=T.m6=T.m7=T.m8 = 0x7fffffff;

#pragma unroll
    for (int b = 0; b < NHALF; ++b) {
        int ci[NCAND];
#pragma unroll
        for (int m = 0; m < NCAND; ++m)
            ci[m] = (int)cand[i * (NHALF * NCAND) + b * NCAND + m];
        float dot[NCAND];
#pragma unroll
        for (int m = 0; m < NCAND; ++m) dot[m] = 0.f;
#pragma unroll 4
        for (int c4 = 0; c4 < 32; ++c4) {
            float4 xv = X4[(size_t)i * 32 + c4];
#pragma unroll
            for (int m = 0; m < NCAND; ++m) {
                float4 nv = X4[(size_t)ci[m] * 32 + c4];
                float a = dot[m];
                a = __builtin_fmaf(xv.x, nv.x, a);
                a = __builtin_fmaf(xv.y, nv.y, a);
                a = __builtin_fmaf(xv.z, nv.z, a);
                a = __builtin_fmaf(xv.w, nv.w, a);
                dot[m] = a;
            }
        }
#pragma unroll
        for (int m = 0; m < NCAND; ++m) {
            float s = __fadd_rn(sqi, sq[ci[m]]);
            float d = __fsub_rn(s, __fmul_rn(2.0f, dot[m]));
            ins9(T, d, ci[m]);
        }
    }

    unsigned short* np = nbr + (size_t)i * KNN;
    np[0]=(unsigned short)T.m0; np[1]=(unsigned short)T.m1; np[2]=(unsigned short)T.m2;
    np[3]=(unsigned short)T.m3; np[4]=(unsigned short)T.m4; np[5]=(unsigned short)T.m5;
    np[6]=(unsigned short)T.m6; np[7]=(unsigned short)T.m7; np[8]=(unsigned short)T.m8;
}

// ---------------- Kernel 3: rel-pos add + max-relative + concat-GEMM ----------------
__global__ __launch_bounds__(256, 2) void out_kernel(const float* __restrict__ x,
                                                     const float* __restrict__ tab,
                                                     const float* __restrict__ W,
                                                     const float* __restrict__ bias,
                                                     const unsigned short* __restrict__ nbr,
                                                     float* __restrict__ out) {
    __shared__ float cat[32][260];
    const int t = threadIdx.x;
    const int row0 = blockIdx.x * 32;
    {
        const int row = t >> 3;
        const int q = t & 7;
        const int i = row0 + row;
        const int rel_i = (i >> 7) - (i & 127) + 127;
        int nb[KNN], reln[KNN];
#pragma unroll
        for (int j = 0; j < KNN; ++j) {
            nb[j] = (int)nbr[i * KNN + j];
            reln[j] = (nb[j] >> 7) - (nb[j] & 127) + 127;
        }
        const float4* X4 = (const float4*)x;
        const float4* T4 = (const float4*)tab;
#pragma unroll
        for (int cc = 0; cc < 4; ++cc) {
            const int c4 = q * 4 + cc;
            float4 xv = X4[i * 32 + c4];
            float4 tv = T4[rel_i * 32 + c4];
            float4 xi;
            xi.x = xv.x + tv.x; xi.y = xv.y + tv.y; xi.z = xv.z + tv.z; xi.w = xv.w + tv.w;
            const float ninf = -__builtin_inff();
            float4 mx = {ninf, ninf, ninf, ninf};
#pragma unroll
            for (int j = 0; j < KNN; ++j) {
                float4 nv = X4[nb[j] * 32 + c4];
                float4 ntv = T4[reln[j] * 32 + c4];
                mx.x = fmaxf(mx.x, nv.x + ntv.x - xi.x);
                mx.y = fmaxf(mx.y, nv.y + ntv.y - xi.y);
                mx.z = fmaxf(mx.z, nv.z + ntv.z - xi.z);
                mx.w = fmaxf(mx.w, nv.w + ntv.w - xi.w);
            }
            *(float4*)&cat[row][c4 * 4] = xi;
            *(float4*)&cat[row][CH + c4 * 4] = mx;
        }
    }
    __syncthreads();

    float acc[32];
    const float bo = bias[t];
#pragma unroll
    for (int i = 0; i < 32; ++i) acc[i] = bo;
#pragma unroll 2
    for (int c0 = 0; c0 < 2 * CH; c0 += 4) {
        const float w0 = W[(c0 + 0) * COUT + t];
        const float w1 = W[(c0 + 1) * COUT + t];
        const float w2 = W[(c0 + 2) * COUT + t];
        const float w3 = W[(c0 + 3) * COUT + t];
#pragma unroll
        for (int i = 0; i < 32; ++i) {
            const float4 cv = *(const float4*)&cat[i][c0];
            acc[i] = fmaf(cv.x, w0, acc[i]);
            acc[i] = fmaf(cv.y, w1, acc[i]);
            acc[i] = fmaf(cv.z, w2, acc[i]);
            acc[i] = fmaf(cv.w, w3, acc[i]);
        }
    }
#pragma unroll
    for (int i = 0; i < 32; ++i) out[(size_t)(row0 + i) * COUT + t] = acc[i];
}

extern "C" void kernel_launch(void* const* d_in, const int* in_sizes, int n_in,
                              void* d_out, int out_size, void* d_ws, size_t ws_size,
                              hipStream_t stream) {
    (void)in_sizes; (void)n_in; (void)out_size; (void)ws_size;
    const float* x = (const float*)d_in[0];
    const float* tab = (const float*)d_in[1];
    const float* W = (const float*)d_in[2];
    const float* b = (const float*)d_in[3];
    float* out = (float*)d_out;

    char* ws = (char*)d_ws;
    float* sq = (float*)ws;                                       // 64 KB
    unsigned short* cand = (unsigned short*)(sq + NPTS);          // N*24 u16 = 768 KB
    unsigned short* nbr = cand + (size_t)NPTS * NHALF * NCAND;    // N*9 u16 = 288 KB
    // total 1.09 MiB < 1.375 MiB proven-safe (round 8)

    sqnp_kernel<<<NPTS / 256, 256, 0, stream>>>(x, sq);
    knn_kernel<<<dim3(NPTS / 64, NHALF), 256, 0, stream>>>(x, sq, cand);
    refine_np_kernel<<<NPTS / 256, 256, 0, stream>>>(x, sq, cand, nbr);
    out_kernel<<<NPTS / 32, 256, 0, stream>>>(x, tab, W, b, nbr, out);
}

// Round 12
// 1802.464 us; speedup vs baseline: 7.5315x; 1.0973x over previous
//
#include <hip/hip_runtime.h>

#define NPTS 16384
#define CH 128
#define KNN 9
#define NCAND 12          // per column-half
#define NHALF 2           // column splits
#define COUT 256

typedef float v2f __attribute__((ext_vector_type(2)));

// Workspace budget: proven safe at 1.375 MiB (round 8); 2.125 MiB corrupted
// harness memory (round 10). Layout below = 1.09 MiB. DO NOT GROW.

// ---- Register-guaranteed top-k lists: named scalars only (no arrays!). ----
// LLVM SROA runs before loop unrolling, so loop-indexed private arrays stay in
// scratch (round 6/7: 5.4 GB scratch writes, VALUBusy 7%). Named members are
// constant-offset accesses from IR-gen -> always promoted to VGPRs.
struct TopL {
    float l0,l1,l2,l3,l4,l5,l6,l7,l8,l9,la,lb;
    int   m0,m1,m2,m3,m4,m5,m6,m7,m8,m9,ma,mb;
};
struct Top9 {
    float l0,l1,l2,l3,l4,l5,l6,l7,l8;
    int   m0,m1,m2,m3,m4,m5,m6,m7,m8;
};

__device__ __forceinline__ bool lexlt(float d, int g, float L, int M) {
    return d < L || (d == L && g < M);
}

__device__ __forceinline__ void ins12(TopL& T, float d, int g) {
    if (!lexlt(d, g, T.lb, T.mb)) return;
    bool b0 = lexlt(d,g,T.l0,T.m0);
    bool b1 = lexlt(d,g,T.l1,T.m1);
    bool b2 = lexlt(d,g,T.l2,T.m2);
    bool b3 = lexlt(d,g,T.l3,T.m3);
    bool b4 = lexlt(d,g,T.l4,T.m4);
    bool b5 = lexlt(d,g,T.l5,T.m5);
    bool b6 = lexlt(d,g,T.l6,T.m6);
    bool b7 = lexlt(d,g,T.l7,T.m7);
    bool b8 = lexlt(d,g,T.l8,T.m8);
    bool b9 = lexlt(d,g,T.l9,T.m9);
    bool ba = lexlt(d,g,T.la,T.ma);
    T.lb = ba ? T.la : d;               T.mb = ba ? T.ma : g;
    T.la = b9 ? T.l9 : (ba ? d : T.la); T.ma = b9 ? T.m9 : (ba ? g : T.ma);
    T.l9 = b8 ? T.l8 : (b9 ? d : T.l9); T.m9 = b8 ? T.m8 : (b9 ? g : T.m9);
    T.l8 = b7 ? T.l7 : (b8 ? d : T.l8); T.m8 = b7 ? T.m7 : (b8 ? g : T.m8);
    T.l7 = b6 ? T.l6 : (b7 ? d : T.l7); T.m7 = b6 ? T.m6 : (b7 ? g : T.m7);
    T.l6 = b5 ? T.l5 : (b6 ? d : T.l6); T.m6 = b5 ? T.m5 : (b6 ? g : T.m6);
    T.l5 = b4 ? T.l4 : (b5 ? d : T.l5); T.m5 = b4 ? T.m4 : (b5 ? g : T.m5);
    T.l4 = b3 ? T.l3 : (b4 ? d : T.l4); T.m4 = b3 ? T.m3 : (b4 ? g : T.m4);
    T.l3 = b2 ? T.l2 : (b3 ? d : T.l3); T.m3 = b2 ? T.m2 : (b3 ? g : T.m3);
    T.l2 = b1 ? T.l1 : (b2 ? d : T.l2); T.m2 = b1 ? T.m1 : (b2 ? g : T.m2);
    T.l1 = b0 ? T.l0 : (b1 ? d : T.l1); T.m1 = b0 ? T.m0 : (b1 ? g : T.m1);
    T.l0 = b0 ? d : T.l0;               T.m0 = b0 ? g : T.m0;
}

__device__ __forceinline__ void ins9(Top9& T, float d, int g) {
    if (!lexlt(d, g, T.l8, T.m8)) return;
    bool b0 = lexlt(d,g,T.l0,T.m0);
    bool b1 = lexlt(d,g,T.l1,T.m1);
    bool b2 = lexlt(d,g,T.l2,T.m2);
    bool b3 = lexlt(d,g,T.l3,T.m3);
    bool b4 = lexlt(d,g,T.l4,T.m4);
    bool b5 = lexlt(d,g,T.l5,T.m5);
    bool b6 = lexlt(d,g,T.l6,T.m6);
    bool b7 = lexlt(d,g,T.l7,T.m7);
    T.l8 = b7 ? T.l7 : d;               T.m8 = b7 ? T.m7 : g;
    T.l7 = b6 ? T.l6 : (b7 ? d : T.l7); T.m7 = b6 ? T.m6 : (b7 ? g : T.m7);
    T.l6 = b5 ? T.l5 : (b6 ? d : T.l6); T.m6 = b5 ? T.m5 : (b6 ? g : T.m6);
    T.l5 = b4 ? T.l4 : (b5 ? d : T.l5); T.m5 = b4 ? T.m4 : (b5 ? g : T.m5);
    T.l4 = b3 ? T.l3 : (b4 ? d : T.l4); T.m4 = b3 ? T.m3 : (b4 ? g : T.m4);
    T.l3 = b2 ? T.l2 : (b3 ? d : T.l3); T.m3 = b2 ? T.m2 : (b3 ? g : T.m3);
    T.l2 = b1 ? T.l1 : (b2 ? d : T.l2); T.m2 = b1 ? T.m1 : (b2 ? g : T.m2);
    T.l1 = b0 ? T.l0 : (b1 ? d : T.l1); T.m1 = b0 ? T.m0 : (b1 ? g : T.m1);
    T.l0 = b0 ? d : T.l0;               T.m0 = b0 ? g : T.m0;
}

__device__ __forceinline__ void merge_shfl(TopL& T, int mask) {
    TopL o;
    o.l0=__shfl_xor(T.l0,mask); o.m0=__shfl_xor(T.m0,mask);
    o.l1=__shfl_xor(T.l1,mask); o.m1=__shfl_xor(T.m1,mask);
    o.l2=__shfl_xor(T.l2,mask); o.m2=__shfl_xor(T.m2,mask);
    o.l3=__shfl_xor(T.l3,mask); o.m3=__shfl_xor(T.m3,mask);
    o.l4=__shfl_xor(T.l4,mask); o.m4=__shfl_xor(T.m4,mask);
    o.l5=__shfl_xor(T.l5,mask); o.m5=__shfl_xor(T.m5,mask);
    o.l6=__shfl_xor(T.l6,mask); o.m6=__shfl_xor(T.m6,mask);
    o.l7=__shfl_xor(T.l7,mask); o.m7=__shfl_xor(T.m7,mask);
    o.l8=__shfl_xor(T.l8,mask); o.m8=__shfl_xor(T.m8,mask);
    o.l9=__shfl_xor(T.l9,mask); o.m9=__shfl_xor(T.m9,mask);
    o.la=__shfl_xor(T.la,mask); o.ma=__shfl_xor(T.ma,mask);
    o.lb=__shfl_xor(T.lb,mask); o.mb=__shfl_xor(T.mb,mask);
    ins12(T,o.l0,o.m0); ins12(T,o.l1,o.m1); ins12(T,o.l2,o.m2);
    ins12(T,o.l3,o.m3); ins12(T,o.l4,o.m4); ins12(T,o.l5,o.m5);
    ins12(T,o.l6,o.m6); ins12(T,o.l7,o.m7); ins12(T,o.l8,o.m8);
    ins12(T,o.l9,o.m9); ins12(T,o.la,o.ma); ins12(T,o.lb,o.mb);
}

// ---------------- Kernel 1: numpy pairwise_sum replica of np.sum(x*x, -1) ----------------
// DO NOT TOUCH: this exact rounding order makes selection match the reference
// bit-for-bit (round 6, absmax 0.0).
__global__ __launch_bounds__(256) void sqnp_kernel(const float* __restrict__ x,
                                                   float* __restrict__ sq) {
    const int i = blockIdx.x * 256 + threadIdx.x;
    const float4* row4 = (const float4*)(x + (size_t)i * CH);
    float r[8];
    {
        float4 a = row4[0], b = row4[1];
        r[0] = __fmul_rn(a.x, a.x); r[1] = __fmul_rn(a.y, a.y);
        r[2] = __fmul_rn(a.z, a.z); r[3] = __fmul_rn(a.w, a.w);
        r[4] = __fmul_rn(b.x, b.x); r[5] = __fmul_rn(b.y, b.y);
        r[6] = __fmul_rn(b.z, b.z); r[7] = __fmul_rn(b.w, b.w);
    }
#pragma unroll
    for (int g = 1; g < 16; ++g) {
        float4 a = row4[2 * g], b = row4[2 * g + 1];
        r[0] = __fadd_rn(r[0], __fmul_rn(a.x, a.x));
        r[1] = __fadd_rn(r[1], __fmul_rn(a.y, a.y));
        r[2] = __fadd_rn(r[2], __fmul_rn(a.z, a.z));
        r[3] = __fadd_rn(r[3], __fmul_rn(a.w, a.w));
        r[4] = __fadd_rn(r[4], __fmul_rn(b.x, b.x));
        r[5] = __fadd_rn(r[5], __fmul_rn(b.y, b.y));
        r[6] = __fadd_rn(r[6], __fmul_rn(b.z, b.z));
        r[7] = __fadd_rn(r[7], __fmul_rn(b.w, b.w));
    }
    float t0 = __fadd_rn(__fadd_rn(r[0], r[1]), __fadd_rn(r[2], r[3]));
    float t1 = __fadd_rn(__fadd_rn(r[4], r[5]), __fadd_rn(r[6], r[7]));
    sq[i] = __fadd_rn(t0, t1);
}

// ---------------- Kernel 2: fused fp32 distance-GEMM + per-half top-12 ----------------
// GEMM micro-kernel on float2 ext-vectors along k -> llvm.fma.v2f32 ->
// v_pk_fma_f32 (dual-issue fp32). Scalar v_fmac was 874 us of pure issue time
// (round-11: VALUBusy 61% x 1925 us = 1174 us busy ~ 874 FMA + 300 overhead);
// packed halves the FMA stream. 157.3 TF fp32 peak REQUIRES pk_fma.
__global__ __launch_bounds__(256, 2) void knn_kernel(const float* __restrict__ x,
                                                     const float* __restrict__ sq,
                                                     unsigned short* __restrict__ cand) {
    __shared__ float Xq[64 * 128];
    __shared__ float Xc[2 * 64 * 64];
    __shared__ float Dist[64 * 64];
    const int t = threadIdx.x;
    const int txl = t >> 4;
    const int ty = t & 15;
    const int row0 = blockIdx.x * 64;
    const int half = blockIdx.y;
    const int ctbeg = half * (NPTS / NHALF);
    const int ctend = ctbeg + NPTS / NHALF;
    const int qsw = (txl & 3) << 4;
    const int csw = ty << 2;

    {
        const float4* xg = (const float4*)(x + (size_t)row0 * CH);
#pragma unroll
        for (int it = 0; it < 8; ++it) {
            int fg = t + it * 256;
            int r = fg >> 5;
            int c4 = fg & 31;
            float4 v = xg[fg];
            *(float4*)&Xq[r * 128 + 4 * (c4 ^ ((r & 3) << 2))] = v;
        }
    }

    float sqr[4];
#pragma unroll
    for (int s = 0; s < 4; ++s) sqr[s] = sq[row0 + txl + 16 * s];

    TopL T;
    T.l0=T.l1=T.l2=T.l3=T.l4=T.l5=T.l6=T.l7=T.l8=T.l9=T.la=T.lb = __builtin_inff();
    T.m0=T.m1=T.m2=T.m3=T.m4=T.m5=T.m6=T.m7=T.m8=T.m9=T.ma=T.mb = 0x7fffffff;

    const int srow = t >> 2;       // selection-phase row (0..63)
    const int sq4 = t & 3;         // selection-phase column quarter
    const int srowg = row0 + srow;

    const float* qp = Xq + txl * 128;
    const float* cp = Xc + ty * 64;

    for (int ct = ctbeg; ct < ctend; ct += 64) {
        const float4* xg = (const float4*)(x + (size_t)ct * CH);
#pragma unroll
        for (int it = 0; it < 8; ++it) {
            int fg = t + it * 256;
            int r = fg >> 5;
            int c4 = fg & 31;
            int h = c4 >> 4;
            int j = c4 & 15;
            float4 v = xg[fg];
            *(float4*)&Xc[h * 4096 + r * 64 + 4 * (j ^ (r & 15))] = v;
        }
        float sqc[4];
#pragma unroll
        for (int u = 0; u < 4; ++u) sqc[u] = sq[ct + ty + 16 * u];
        __syncthreads();

        v2f acc2[4][4];
#pragma unroll
        for (int s = 0; s < 4; ++s)
#pragma unroll
            for (int u = 0; u < 4; ++u) acc2[s][u] = (v2f)(0.f);

#pragma unroll 4
        for (int k0 = 0; k0 < CH; k0 += 4) {
            const int qo = k0 ^ qsw;
            const int co = ((k0 >> 6) * 4096) + ((k0 & 63) ^ csw);
            v2f alo[4], ahi[4], blo[4], bhi[4];
#pragma unroll
            for (int s = 0; s < 4; ++s) {
                const v2f* ap = (const v2f*)(qp + s * 2048 + qo);
                alo[s] = ap[0]; ahi[s] = ap[1];
            }
#pragma unroll
            for (int u = 0; u < 4; ++u) {
                const v2f* bp = (const v2f*)(cp + u * 1024 + co);
                blo[u] = bp[0]; bhi[u] = bp[1];
            }
#pragma unroll
            for (int s = 0; s < 4; ++s)
#pragma unroll
                for (int u = 0; u < 4; ++u) {
                    acc2[s][u] = __builtin_elementwise_fma(alo[s], blo[u], acc2[s][u]);
                    acc2[s][u] = __builtin_elementwise_fma(ahi[s], bhi[u], acc2[s][u]);
                }
        }

        // distances -> Dist LDS, physical col = col ^ row
#pragma unroll
        for (int s = 0; s < 4; ++s) {
            const int row = txl + 16 * s;
#pragma unroll
            for (int u = 0; u < 4; ++u) {
                const int col = ty + 16 * u;
                const float dot = acc2[s][u].x + acc2[s][u].y;
                Dist[row * 64 + (col ^ row)] = sqr[s] + sqc[u] - 2.f * dot;
            }
        }
        __syncthreads();

        // selection scan: 16 candidates from this tile for row srow
#pragma unroll
        for (int k = 0; k < 16; ++k) {
            const int col = sq4 * 16 + k;
            const float d = Dist[srow * 64 + (col ^ srow)];
            const int cg = ct + col;
            if (cg != srowg) ins12(T, d, cg);
        }
    }

    // merge the 4 partial lists per row (lanes t^1, t^2 share srow)
    merge_shfl(T, 1);
    merge_shfl(T, 2);

    if (sq4 == 0) {
        unsigned short* cp_out = cand + (size_t)srowg * (NHALF * NCAND) + half * NCAND;
        cp_out[0]=(unsigned short)T.m0; cp_out[1]=(unsigned short)T.m1;
        cp_out[2]=(unsigned short)T.m2; cp_out[3]=(unsigned short)T.m3;
        cp_out[4]=(unsigned short)T.m4; cp_out[5]=(unsigned short)T.m5;
        cp_out[6]=(unsigned short)T.m6; cp_out[7]=(unsigned short)T.m7;
        cp_out[8]=(unsigned short)T.m8; cp_out[9]=(unsigned short)T.m9;
        cp_out[10]=(unsigned short)T.ma; cp_out[11]=(unsigned short)T.mb;
    }
}

// ---------------- Kernel 2.5: numpy-fp32-replica re-rank of 24 candidates ----------------
// dot: BLAS sgemm per-element rounding = ONE accumulator, sequential ascending-k FMA.
// d  : fl( fl(sq_i + sq_j) - fl(2*dot) ).
// DO NOT TOUCH the rounding order — verified exact vs reference (round 6, absmax 0.0).
__global__ __launch_bounds__(256) void refine_np_kernel(const float* __restrict__ x,
                                                        const float* __restrict__ sq,
                                                        const unsigned short* __restrict__ cand,
                                                        unsigned short* __restrict__ nbr) {
    const int i = blockIdx.x * 256 + threadIdx.x;
    const float4* X4 = (const float4*)x;
    const float sqi = sq[i];

    Top9 T;
    T.l0=T.l1=T.l2=T.l3=T.l4=T.l5=T.l6=T.l7=T.l8 = __builtin_inff();
    T.m0=T.m1=T.m2=T.m3=T.m4=T.m5=T.m6=T.m7=T.m8 = 0x7fffffff;

#pragma unroll
    for (int b = 0; b < NHALF; ++b) {
        int ci[NCAND];
#pragma unroll
        for (int m = 0; m < NCAND; ++m)
            ci[m] = (int)cand[i * (NHALF * NCAND) + b * NCAND + m];
        float dot[NCAND];
#pragma unroll
        for (int m = 0; m < NCAND; ++m) dot[m] = 0.f;
#pragma unroll 4
        for (int c4 = 0; c4 < 32; ++c4) {
            float4 xv = X4[(size_t)i * 32 + c4];
#pragma unroll
            for (int m = 0; m < NCAND; ++m) {
                float4 nv = X4[(size_t)ci[m] * 32 + c4];
                float a = dot[m];
                a = __builtin_fmaf(xv.x, nv.x, a);
                a = __builtin_fmaf(xv.y, nv.y, a);
                a = __builtin_fmaf(xv.z, nv.z, a);
                a = __builtin_fmaf(xv.w, nv.w, a);
                dot[m] = a;
            }
        }
#pragma unroll
        for (int m = 0; m < NCAND; ++m) {
            float s = __fadd_rn(sqi, sq[ci[m]]);
            float d = __fsub_rn(s, __fmul_rn(2.0f, dot[m]));
            ins9(T, d, ci[m]);
        }
    }

    unsigned short* np = nbr + (size_t)i * KNN;
    np[0]=(unsigned short)T.m0; np[1]=(unsigned short)T.m1; np[2]=(unsigned short)T.m2;
    np[3]=(unsigned short)T.m3; np[4]=(unsigned short)T.m4; np[5]=(unsigned short)T.m5;
    np[6]=(unsigned short)T.m6; np[7]=(unsigned short)T.m7; np[8]=(unsigned short)T.m8;
}

// ---------------- Kernel 3: rel-pos add + max-relative + concat-GEMM ----------------
__global__ __launch_bounds__(256, 2) void out_kernel(const float* __restrict__ x,
                                                     const float* __restrict__ tab,
                                                     const float* __restrict__ W,
                                                     const float* __restrict__ bias,
                                                     const unsigned short* __restrict__ nbr,
                                                     float* __restrict__ out) {
    __shared__ float cat[32][260];
    const int t = threadIdx.x;
    const int row0 = blockIdx.x * 32;
    {
        const int row = t >> 3;
        const int q = t & 7;
        const int i = row0 + row;
        const int rel_i = (i >> 7) - (i & 127) + 127;
        int nb[KNN], reln[KNN];
#pragma unroll
        for (int j = 0; j < KNN; ++j) {
            nb[j] = (int)nbr[i * KNN + j];
            reln[j] = (nb[j] >> 7) - (nb[j] & 127) + 127;
        }
        const float4* X4 = (const float4*)x;
        const float4* T4 = (const float4*)tab;
#pragma unroll
        for (int cc = 0; cc < 4; ++cc) {
            const int c4 = q * 4 + cc;
            float4 xv = X4[i * 32 + c4];
            float4 tv = T4[rel_i * 32 + c4];
            float4 xi;
            xi.x = xv.x + tv.x; xi.y = xv.y + tv.y; xi.z = xv.z + tv.z; xi.w = xv.w + tv.w;
            const float ninf = -__builtin_inff();
            float4 mx = {ninf, ninf, ninf, ninf};
#pragma unroll
            for (int j = 0; j < KNN; ++j) {
                float4 nv = X4[nb[j] * 32 + c4];
                float4 ntv = T4[reln[j] * 32 + c4];
                mx.x = fmaxf(mx.x, nv.x + ntv.x - xi.x);
                mx.y = fmaxf(mx.y, nv.y + ntv.y - xi.y);
                mx.z = fmaxf(mx.z, nv.z + ntv.z - xi.z);
                mx.w = fmaxf(mx.w, nv.w + ntv.w - xi.w);
            }
            *(float4*)&cat[row][c4 * 4] = xi;
            *(float4*)&cat[row][CH + c4 * 4] = mx;
        }
    }
    __syncthreads();

    float acc[32];
    const float bo = bias[t];
#pragma unroll
    for (int i = 0; i < 32; ++i) acc[i] = bo;
#pragma unroll 2
    for (int c0 = 0; c0 < 2 * CH; c0 += 4) {
        const float w0 = W[(c0 + 0) * COUT + t];
        const float w1 = W[(c0 + 1) * COUT + t];
        const float w2 = W[(c0 + 2) * COUT + t];
        const float w3 = W[(c0 + 3) * COUT + t];
#pragma unroll
        for (int i = 0; i < 32; ++i) {
            const float4 cv = *(const float4*)&cat[i][c0];
            acc[i] = fmaf(cv.x, w0, acc[i]);
            acc[i] = fmaf(cv.y, w1, acc[i]);
            acc[i] = fmaf(cv.z, w2, acc[i]);
            acc[i] = fmaf(cv.w, w3, acc[i]);
        }
    }
#pragma unroll
    for (int i = 0; i < 32; ++i) out[(size_t)(row0 + i) * COUT + t] = acc[i];
}

extern "C" void kernel_launch(void* const* d_in, const int* in_sizes, int n_in,
                              void* d_out, int out_size, void* d_ws, size_t ws_size,
                              hipStream_t stream) {
    (void)in_sizes; (void)n_in; (void)out_size; (void)ws_size;
    const float* x = (const float*)d_in[0];
    const float* tab = (const float*)d_in[1];
    const float* W = (const float*)d_in[2];
    const float* b = (const float*)d_in[3];
    float* out = (float*)d_out;

    char* ws = (char*)d_ws;
    float* sq = (float*)ws;                                       // 64 KB
    unsigned short* cand = (unsigned short*)(sq + NPTS);          // N*24 u16 = 768 KB
    unsigned short* nbr = cand + (size_t)NPTS * NHALF * NCAND;    // N*9 u16 = 288 KB
    // total 1.09 MiB < 1.375 MiB proven-safe (round 8)

    sqnp_kernel<<<NPTS / 256, 256, 0, stream>>>(x, sq);
    knn_kernel<<<dim3(NPTS / 64, NHALF), 256, 0, stream>>>(x, sq, cand);
    refine_np_kernel<<<NPTS / 256, 256, 0, stream>>>(x, sq, cand, nbr);
    out_kernel<<<NPTS / 32, 256, 0, stream>>>(x, tab, W, b, nbr, out);
}

// Round 13
// 1234.318 us; speedup vs baseline: 10.9982x; 1.4603x over previous
//
#include <hip/hip_runtime.h>

#define NPTS 16384
#define CH 128
#define KNN 9
#define NCAND 12          // per column-half
#define NHALF 2           // column splits
#define COUT 256

typedef __attribute__((ext_vector_type(8))) short bf16x8;
typedef __attribute__((ext_vector_type(4))) float f32x4;

// Workspace budget: proven safe at 1.375 MiB (round 8); 2.125 MiB corrupted
// harness memory (round 10). Layout below = 1.09 MiB. DO NOT GROW.

// Split f -> bf16 hi + bf16 lo (RNE). h/l are packed pairs (x0 low, x1 high).
// hi subtraction is exact in fp32; dropped lo*lo term ~2^-18 rel -> distance
// error ~1e-4 abs, far below the per-half rank-12 candidate margin (~2.7).
__device__ __forceinline__ void bfsplit2(float x0, float x1, unsigned& h, unsigned& l) {
    unsigned u0 = __float_as_uint(x0), u1 = __float_as_uint(x1);
    unsigned r0 = (u0 + 0x7fffu + ((u0 >> 16) & 1u)) & 0xffff0000u;
    unsigned r1 = (u1 + 0x7fffu + ((u1 >> 16) & 1u)) & 0xffff0000u;
    float lo0 = x0 - __uint_as_float(r0);
    float lo1 = x1 - __uint_as_float(r1);
    unsigned v0 = __float_as_uint(lo0), v1 = __float_as_uint(lo1);
    unsigned s0 = (v0 + 0x7fffu + ((v0 >> 16) & 1u));
    unsigned s1 = (v1 + 0x7fffu + ((v1 >> 16) & 1u));
    h = (r0 >> 16) | r1;
    l = (s0 >> 16) | (s1 & 0xffff0000u);
}

// ---- Register-guaranteed top-k lists: named scalars only (no arrays!). ----
// LLVM SROA runs before loop unrolling, so loop-indexed private arrays stay in
// scratch (round 6/7: 5.4 GB scratch writes, VALUBusy 7%).
struct TopL {
    float l0,l1,l2,l3,l4,l5,l6,l7,l8,l9,la,lb;
    int   m0,m1,m2,m3,m4,m5,m6,m7,m8,m9,ma,mb;
};
struct Top9 {
    float l0,l1,l2,l3,l4,l5,l6,l7,l8;
    int   m0,m1,m2,m3,m4,m5,m6,m7,m8;
};

__device__ __forceinline__ bool lexlt(float d, int g, float L, int M) {
    return d < L || (d == L && g < M);
}

__device__ __forceinline__ void ins12(TopL& T, float d, int g) {
    if (!lexlt(d, g, T.lb, T.mb)) return;
    bool b0 = lexlt(d,g,T.l0,T.m0);
    bool b1 = lexlt(d,g,T.l1,T.m1);
    bool b2 = lexlt(d,g,T.l2,T.m2);
    bool b3 = lexlt(d,g,T.l3,T.m3);
    bool b4 = lexlt(d,g,T.l4,T.m4);
    bool b5 = lexlt(d,g,T.l5,T.m5);
    bool b6 = lexlt(d,g,T.l6,T.m6);
    bool b7 = lexlt(d,g,T.l7,T.m7);
    bool b8 = lexlt(d,g,T.l8,T.m8);
    bool b9 = lexlt(d,g,T.l9,T.m9);
    bool ba = lexlt(d,g,T.la,T.ma);
    T.lb = ba ? T.la : d;               T.mb = ba ? T.ma : g;
    T.la = b9 ? T.l9 : (ba ? d : T.la); T.ma = b9 ? T.m9 : (ba ? g : T.ma);
    T.l9 = b8 ? T.l8 : (b9 ? d : T.l9); T.m9 = b8 ? T.m8 : (b9 ? g : T.m9);
    T.l8 = b7 ? T.l7 : (b8 ? d : T.l8); T.m8 = b7 ? T.m7 : (b8 ? g : T.m8);
    T.l7 = b6 ? T.l6 : (b7 ? d : T.l7); T.m7 = b6 ? T.m6 : (b7 ? g : T.m7);
    T.l6 = b5 ? T.l5 : (b6 ? d : T.l6); T.m6 = b5 ? T.m5 : (b6 ? g : T.m6);
    T.l5 = b4 ? T.l4 : (b5 ? d : T.l5); T.m5 = b4 ? T.m4 : (b5 ? g : T.m5);
    T.l4 = b3 ? T.l3 : (b4 ? d : T.l4); T.m4 = b3 ? T.m3 : (b4 ? g : T.m4);
    T.l3 = b2 ? T.l2 : (b3 ? d : T.l3); T.m3 = b2 ? T.m2 : (b3 ? g : T.m3);
    T.l2 = b1 ? T.l1 : (b2 ? d : T.l2); T.m2 = b1 ? T.m1 : (b2 ? g : T.m2);
    T.l1 = b0 ? T.l0 : (b1 ? d : T.l1); T.m1 = b0 ? T.m0 : (b1 ? g : T.m1);
    T.l0 = b0 ? d : T.l0;               T.m0 = b0 ? g : T.m0;
}

__device__ __forceinline__ void ins9(Top9& T, float d, int g) {
    if (!lexlt(d, g, T.l8, T.m8)) return;
    bool b0 = lexlt(d,g,T.l0,T.m0);
    bool b1 = lexlt(d,g,T.l1,T.m1);
    bool b2 = lexlt(d,g,T.l2,T.m2);
    bool b3 = lexlt(d,g,T.l3,T.m3);
    bool b4 = lexlt(d,g,T.l4,T.m4);
    bool b5 = lexlt(d,g,T.l5,T.m5);
    bool b6 = lexlt(d,g,T.l6,T.m6);
    bool b7 = lexlt(d,g,T.l7,T.m7);
    T.l8 = b7 ? T.l7 : d;               T.m8 = b7 ? T.m7 : g;
    T.l7 = b6 ? T.l6 : (b7 ? d : T.l7); T.m7 = b6 ? T.m6 : (b7 ? g : T.m7);
    T.l6 = b5 ? T.l5 : (b6 ? d : T.l6); T.m6 = b5 ? T.m5 : (b6 ? g : T.m6);
    T.l5 = b4 ? T.l4 : (b5 ? d : T.l5); T.m5 = b4 ? T.m4 : (b5 ? g : T.m5);
    T.l4 = b3 ? T.l3 : (b4 ? d : T.l4); T.m4 = b3 ? T.m3 : (b4 ? g : T.m4);
    T.l3 = b2 ? T.l2 : (b3 ? d : T.l3); T.m3 = b2 ? T.m2 : (b3 ? g : T.m3);
    T.l2 = b1 ? T.l1 : (b2 ? d : T.l2); T.m2 = b1 ? T.m1 : (b2 ? g : T.m2);
    T.l1 = b0 ? T.l0 : (b1 ? d : T.l1); T.m1 = b0 ? T.m0 : (b1 ? g : T.m1);
    T.l0 = b0 ? d : T.l0;               T.m0 = b0 ? g : T.m0;
}

__device__ __forceinline__ void merge_shfl(TopL& T, int mask) {
    TopL o;
    o.l0=__shfl_xor(T.l0,mask); o.m0=__shfl_xor(T.m0,mask);
    o.l1=__shfl_xor(T.l1,mask); o.m1=__shfl_xor(T.m1,mask);
    o.l2=__shfl_xor(T.l2,mask); o.m2=__shfl_xor(T.m2,mask);
    o.l3=__shfl_xor(T.l3,mask); o.m3=__shfl_xor(T.m3,mask);
    o.l4=__shfl_xor(T.l4,mask); o.m4=__shfl_xor(T.m4,mask);
    o.l5=__shfl_xor(T.l5,mask); o.m5=__shfl_xor(T.m5,mask);
    o.l6=__shfl_xor(T.l6,mask); o.m6=__shfl_xor(T.m6,mask);
    o.l7=__shfl_xor(T.l7,mask); o.m7=__shfl_xor(T.m7,mask);
    o.l8=__shfl_xor(T.l8,mask); o.m8=__shfl_xor(T.m8,mask);
    o.l9=__shfl_xor(T.l9,mask); o.m9=__shfl_xor(T.m9,mask);
    o.la=__shfl_xor(T.la,mask); o.ma=__shfl_xor(T.ma,mask);
    o.lb=__shfl_xor(T.lb,mask); o.mb=__shfl_xor(T.mb,mask);
    ins12(T,o.l0,o.m0); ins12(T,o.l1,o.m1); ins12(T,o.l2,o.m2);
    ins12(T,o.l3,o.m3); ins12(T,o.l4,o.m4); ins12(T,o.l5,o.m5);
    ins12(T,o.l6,o.m6); ins12(T,o.l7,o.m7); ins12(T,o.l8,o.m8);
    ins12(T,o.l9,o.m9); ins12(T,o.la,o.ma); ins12(T,o.lb,o.mb);
}

// ---------------- Kernel 1: numpy pairwise_sum replica of np.sum(x*x, -1) ----------------
// DO NOT TOUCH: this exact rounding order makes selection match the reference
// bit-for-bit (round 6, absmax 0.0).
__global__ __launch_bounds__(256) void sqnp_kernel(const float* __restrict__ x,
                                                   float* __restrict__ sq) {
    const int i = blockIdx.x * 256 + threadIdx.x;
    const float4* row4 = (const float4*)(x + (size_t)i * CH);
    float r[8];
    {
        float4 a = row4[0], b = row4[1];
        r[0] = __fmul_rn(a.x, a.x); r[1] = __fmul_rn(a.y, a.y);
        r[2] = __fmul_rn(a.z, a.z); r[3] = __fmul_rn(a.w, a.w);
        r[4] = __fmul_rn(b.x, b.x); r[5] = __fmul_rn(b.y, b.y);
        r[6] = __fmul_rn(b.z, b.z); r[7] = __fmul_rn(b.w, b.w);
    }
#pragma unroll
    for (int g = 1; g < 16; ++g) {
        float4 a = row4[2 * g], b = row4[2 * g + 1];
        r[0] = __fadd_rn(r[0], __fmul_rn(a.x, a.x));
        r[1] = __fadd_rn(r[1], __fmul_rn(a.y, a.y));
        r[2] = __fadd_rn(r[2], __fmul_rn(a.z, a.z));
        r[3] = __fadd_rn(r[3], __fmul_rn(a.w, a.w));
        r[4] = __fadd_rn(r[4], __fmul_rn(b.x, b.x));
        r[5] = __fadd_rn(r[5], __fmul_rn(b.y, b.y));
        r[6] = __fadd_rn(r[6], __fmul_rn(b.z, b.z));
        r[7] = __fadd_rn(r[7], __fmul_rn(b.w, b.w));
    }
    float t0 = __fadd_rn(__fadd_rn(r[0], r[1]), __fadd_rn(r[2], r[3]));
    float t1 = __fadd_rn(__fadd_rn(r[4], r[5]), __fadd_rn(r[6], r[7]));
    sq[i] = __fadd_rn(t0, t1);
}

// ------------- Kernel 2: split-bf16 MFMA distance-GEMM + per-half top-12 --------------
// dot = hi*hi + hi*lo + lo*hi via mfma_f32_16x16x32_bf16 (3 MFMA per k-chunk).
// LDS: Ahi/Alo/Bhi/Blo[64][128] bf16, 16B slots XOR-swizzled (slot ^= row&15)
// -> frag ds_read_b128 <=2-way, no padding -> exactly 80 KiB with Dist -> 2 blk/CU.
// Fragment layouts (m89/m120 verified): A[m=lane&15][k=quad*8+j]; C/D col=lane&15,
// row=quad*4+reg. Wave w computes rows [16w,16w+16) x all 64 cols.
__global__ __launch_bounds__(256, 2) void knn_kernel(const float* __restrict__ x,
                                                     const float* __restrict__ sq,
                                                     unsigned short* __restrict__ cand) {
    __shared__ short Ahi[64 * 128];
    __shared__ short Alo[64 * 128];
    __shared__ short Bhi[64 * 128];
    __shared__ short Blo[64 * 128];
    __shared__ float Dist[64 * 64];
    const int t = threadIdx.x;
    const int row0 = blockIdx.x * 64;
    const int half = blockIdx.y;
    const int ctbeg = half * (NPTS / NHALF);
    const int ctend = ctbeg + NPTS / NHALF;

    // ---- stage A (query rows) once: fp32 -> bf16 hi/lo, swizzled slots ----
#pragma unroll
    for (int it = 0; it < 4; ++it) {
        int P = t + it * 256;        // 0..1023: (row, slot)
        int r = P >> 4;
        int s = P & 15;
        int phys = s ^ (r & 15);
        const float4* src = (const float4*)(x + (size_t)(row0 + r) * CH) + s * 2;
        float4 f0 = src[0], f1 = src[1];
        uint4 h, l;
        bfsplit2(f0.x, f0.y, h.x, l.x);
        bfsplit2(f0.z, f0.w, h.y, l.y);
        bfsplit2(f1.x, f1.y, h.z, l.z);
        bfsplit2(f1.z, f1.w, h.w, l.w);
        *(uint4*)&Ahi[r * 128 + phys * 8] = h;
        *(uint4*)&Alo[r * 128 + phys * 8] = l;
    }

    const int lane = t & 63;
    const int w = t >> 6;          // wave id: rows [16w, 16w+16)
    const int m = lane & 15;
    const int quad = lane >> 4;
    const float4 sqr4 = *(const float4*)&sq[row0 + 16 * w + quad * 4];

    TopL T;
    T.l0=T.l1=T.l2=T.l3=T.l4=T.l5=T.l6=T.l7=T.l8=T.l9=T.la=T.lb = __builtin_inff();
    T.m0=T.m1=T.m2=T.m3=T.m4=T.m5=T.m6=T.m7=T.m8=T.m9=T.ma=T.mb = 0x7fffffff;

    const int srow = t >> 2;       // selection-phase row (0..63)
    const int sq4 = t & 3;         // selection-phase column quarter
    const int srowg = row0 + srow;

    for (int ct = ctbeg; ct < ctend; ct += 64) {
        // ---- stage B tile: fp32 -> bf16 hi/lo, swizzled ----
#pragma unroll
        for (int it = 0; it < 4; ++it) {
            int P = t + it * 256;
            int r = P >> 4;
            int s = P & 15;
            int phys = s ^ (r & 15);
            const float4* src = (const float4*)(x + (size_t)(ct + r) * CH) + s * 2;
            float4 f0 = src[0], f1 = src[1];
            uint4 h, l;
            bfsplit2(f0.x, f0.y, h.x, l.x);
            bfsplit2(f0.z, f0.w, h.y, l.y);
            bfsplit2(f1.x, f1.y, h.z, l.z);
            bfsplit2(f1.z, f1.w, h.w, l.w);
            *(uint4*)&Bhi[r * 128 + phys * 8] = h;
            *(uint4*)&Blo[r * 128 + phys * 8] = l;
        }
        __syncthreads();

        const float sqc0 = sq[ct + 0  + m];
        const float sqc1 = sq[ct + 16 + m];
        const float sqc2 = sq[ct + 32 + m];
        const float sqc3 = sq[ct + 48 + m];

        f32x4 acc0 = {0.f,0.f,0.f,0.f};
        f32x4 acc1 = {0.f,0.f,0.f,0.f};
        f32x4 acc2 = {0.f,0.f,0.f,0.f};
        f32x4 acc3 = {0.f,0.f,0.f,0.f};

#pragma unroll
        for (int kc = 0; kc < 4; ++kc) {
            const int ks = ((kc * 4 + quad) ^ m) * 8;
            const int ar = (16 * w + m) * 128 + ks;
            bf16x8 ah = *(const bf16x8*)&Ahi[ar];
            bf16x8 al = *(const bf16x8*)&Alo[ar];
            bf16x8 bh0 = *(const bf16x8*)&Bhi[(0  + m) * 128 + ks];
            bf16x8 bl0 = *(const bf16x8*)&Blo[(0  + m) * 128 + ks];
            bf16x8 bh1 = *(const bf16x8*)&Bhi[(16 + m) * 128 + ks];
            bf16x8 bl1 = *(const bf16x8*)&Blo[(16 + m) * 128 + ks];
            bf16x8 bh2 = *(const bf16x8*)&Bhi[(32 + m) * 128 + ks];
            bf16x8 bl2 = *(const bf16x8*)&Blo[(32 + m) * 128 + ks];
            bf16x8 bh3 = *(const bf16x8*)&Bhi[(48 + m) * 128 + ks];
            bf16x8 bl3 = *(const bf16x8*)&Blo[(48 + m) * 128 + ks];
            acc0 = __builtin_amdgcn_mfma_f32_16x16x32_bf16(ah, bh0, acc0, 0, 0, 0);
            acc0 = __builtin_amdgcn_mfma_f32_16x16x32_bf16(ah, bl0, acc0, 0, 0, 0);
            acc0 = __builtin_amdgcn_mfma_f32_16x16x32_bf16(al, bh0, acc0, 0, 0, 0);
            acc1 = __builtin_amdgcn_mfma_f32_16x16x32_bf16(ah, bh1, acc1, 0, 0, 0);
            acc1 = __builtin_amdgcn_mfma_f32_16x16x32_bf16(ah, bl1, acc1, 0, 0, 0);
            acc1 = __builtin_amdgcn_mfma_f32_16x16x32_bf16(al, bh1, acc1, 0, 0, 0);
            acc2 = __builtin_amdgcn_mfma_f32_16x16x32_bf16(ah, bh2, acc2, 0, 0, 0);
            acc2 = __builtin_amdgcn_mfma_f32_16x16x32_bf16(ah, bl2, acc2, 0, 0, 0);
            acc2 = __builtin_amdgcn_mfma_f32_16x16x32_bf16(al, bh2, acc2, 0, 0, 0);
            acc3 = __builtin_amdgcn_mfma_f32_16x16x32_bf16(ah, bh3, acc3, 0, 0, 0);
            acc3 = __builtin_amdgcn_mfma_f32_16x16x32_bf16(ah, bl3, acc3, 0, 0, 0);
            acc3 = __builtin_amdgcn_mfma_f32_16x16x32_bf16(al, bh3, acc3, 0, 0, 0);
        }

        // D (col=lane&15, row=quad*4+reg) -> Dist LDS, physical col = col ^ row
#pragma unroll
        for (int reg = 0; reg < 4; ++reg) {
            const int row = 16 * w + quad * 4 + reg;
            const float sqr_r = (reg == 0) ? sqr4.x : (reg == 1) ? sqr4.y
                              : (reg == 2) ? sqr4.z : sqr4.w;
            const int c0 = 0  + m;
            const int c1 = 16 + m;
            const int c2 = 32 + m;
            const int c3 = 48 + m;
            Dist[row * 64 + (c0 ^ row)] = sqr_r + sqc0 - 2.f * acc0[reg];
            Dist[row * 64 + (c1 ^ row)] = sqr_r + sqc1 - 2.f * acc1[reg];
            Dist[row * 64 + (c2 ^ row)] = sqr_r + sqc2 - 2.f * acc2[reg];
            Dist[row * 64 + (c3 ^ row)] = sqr_r + sqc3 - 2.f * acc3[reg];
        }
        __syncthreads();

        // selection scan: 16 candidates from this tile for row srow
#pragma unroll
        for (int k = 0; k < 16; ++k) {
            const int col = sq4 * 16 + k;
            const float d = Dist[srow * 64 + (col ^ srow)];
            const int cg = ct + col;
            if (cg != srowg) ins12(T, d, cg);
        }
    }

    // merge the 4 partial lists per row (lanes t^1, t^2 share srow)
    merge_shfl(T, 1);
    merge_shfl(T, 2);

    if (sq4 == 0) {
        unsigned short* cp_out = cand + (size_t)srowg * (NHALF * NCAND) + half * NCAND;
        cp_out[0]=(unsigned short)T.m0; cp_out[1]=(unsigned short)T.m1;
        cp_out[2]=(unsigned short)T.m2; cp_out[3]=(unsigned short)T.m3;
        cp_out[4]=(unsigned short)T.m4; cp_out[5]=(unsigned short)T.m5;
        cp_out[6]=(unsigned short)T.m6; cp_out[7]=(unsigned short)T.m7;
        cp_out[8]=(unsigned short)T.m8; cp_out[9]=(unsigned short)T.m9;
        cp_out[10]=(unsigned short)T.ma; cp_out[11]=(unsigned short)T.mb;
    }
}

// ---------------- Kernel 2.5: numpy-fp32-replica re-rank of 24 candidates ----------------
// dot: BLAS sgemm per-element rounding = ONE accumulator, sequential ascending-k FMA.
// d  : fl( fl(sq_i + sq_j) - fl(2*dot) ).
// DO NOT TOUCH the rounding order — verified exact vs reference (round 6, absmax 0.0).
__global__ __launch_bounds__(256) void refine_np_kernel(const float* __restrict__ x,
                                                        const float* __restrict__ sq,
                                                        const unsigned short* __restrict__ cand,
                                                        unsigned short* __restrict__ nbr) {
    const int i = blockIdx.x * 256 + threadIdx.x;
    const float4* X4 = (const float4*)x;
    const float sqi = sq[i];

    Top9 T;
    T.l0=T.l1=T.l2=T.l3=T.l4=T.l5=T.l6=T.l7=T.l8 = __builtin_inff();
    T.m0=T.m1=T.m2=T.m3=T.m4=T.m5=T.m6=T.m7=T.m8 = 0x7fffffff;

#pragma unroll
    for (int b = 0; b < NHALF; ++b) {
        int ci[NCAND];
#pragma unroll
        for (int m = 0; m < NCAND; ++m)
            ci[m] = (int)cand[i * (NHALF * NCAND) + b * NCAND + m];
        float dot[NCAND];
#pragma unroll
        for (int m = 0; m < NCAND; ++m) dot[m] = 0.f;
#pragma unroll 4
        for (int c4 = 0; c4 < 32; ++c4) {
            float4 xv = X4[(size_t)i * 32 + c4];
#pragma unroll
            for (int m = 0; m < NCAND; ++m) {
                float4 nv = X4[(size_t)ci[m] * 32 + c4];
                float a = dot[m];
                a = __builtin_fmaf(xv.x, nv.x, a);
                a = __builtin_fmaf(xv.y, nv.y, a);
                a = __builtin_fmaf(xv.z, nv.z, a);
                a = __builtin_fmaf(xv.w, nv.w, a);
                dot[m] = a;
            }
        }
#pragma unroll
        for (int m = 0; m < NCAND; ++m) {
            float s = __fadd_rn(sqi, sq[ci[m]]);
            float d = __fsub_rn(s, __fmul_rn(2.0f, dot[m]));
            ins9(T, d, ci[m]);
        }
    }

    unsigned short* np = nbr + (size_t)i * KNN;
    np[0]=(unsigned short)T.m0; np[1]=(unsigned short)T.m1; np[2]=(unsigned short)T.m2;
    np[3]=(unsigned short)T.m3; np[4]=(unsigned short)T.m4; np[5]=(unsigned short)T.m5;
    np[6]=(unsigned short)T.m6; np[7]=(unsigned short)T.m7; np[8]=(unsigned short)T.m8;
}

// ---------------- Kernel 3: rel-pos add + max-relative + concat-GEMM ----------------
__global__ __launch_bounds__(256, 2) void out_kernel(const float* __restrict__ x,
                                                     const float* __restrict__ tab,
                                                     const float* __restrict__ W,
                                                     const float* __restrict__ bias,
                                                     const unsigned short* __restrict__ nbr,
                                                     float* __restrict__ out) {
    __shared__ float cat[32][260];
    const int t = threadIdx.x;
    const int row0 = blockIdx.x * 32;
    {
        const int row = t >> 3;
        const int q = t & 7;
        const int i = row0 + row;
        const int rel_i = (i >> 7) - (i & 127) + 127;
        int nb[KNN], reln[KNN];
#pragma unroll
        for (int j = 0; j < KNN; ++j) {
            nb[j] = (int)nbr[i * KNN + j];
            reln[j] = (nb[j] >> 7) - (nb[j] & 127) + 127;
        }
        const float4* X4 = (const float4*)x;
        const float4* T4 = (const float4*)tab;
#pragma unroll
        for (int cc = 0; cc < 4; ++cc) {
            const int c4 = q * 4 + cc;
            float4 xv = X4[i * 32 + c4];
            float4 tv = T4[rel_i * 32 + c4];
            float4 xi;
            xi.x = xv.x + tv.x; xi.y = xv.y + tv.y; xi.z = xv.z + tv.z; xi.w = xv.w + tv.w;
            const float ninf = -__builtin_inff();
            float4 mx = {ninf, ninf, ninf, ninf};
#pragma unroll
            for (int j = 0; j < KNN; ++j) {
                float4 nv = X4[nb[j] * 32 + c4];
                float4 ntv = T4[reln[j] * 32 + c4];
                mx.x = fmaxf(mx.x, nv.x + ntv.x - xi.x);
                mx.y = fmaxf(mx.y, nv.y + ntv.y - xi.y);
                mx.z = fmaxf(mx.z, nv.z + ntv.z - xi.z);
                mx.w = fmaxf(mx.w, nv.w + ntv.w - xi.w);
            }
            *(float4*)&cat[row][c4 * 4] = xi;
            *(float4*)&cat[row][CH + c4 * 4] = mx;
        }
    }
    __syncthreads();

    float acc[32];
    const float bo = bias[t];
#pragma unroll
    for (int i = 0; i < 32; ++i) acc[i] = bo;
#pragma unroll 2
    for (int c0 = 0; c0 < 2 * CH; c0 += 4) {
        const float w0 = W[(c0 + 0) * COUT + t];
        const float w1 = W[(c0 + 1) * COUT + t];
        const float w2 = W[(c0 + 2) * COUT + t];
        const float w3 = W[(c0 + 3) * COUT + t];
#pragma unroll
        for (int i = 0; i < 32; ++i) {
            const float4 cv = *(const float4*)&cat[i][c0];
            acc[i] = fmaf(cv.x, w0, acc[i]);
            acc[i] = fmaf(cv.y, w1, acc[i]);
            acc[i] = fmaf(cv.z, w2, acc[i]);
            acc[i] = fmaf(cv.w, w3, acc[i]);
        }
    }
#pragma unroll
    for (int i = 0; i < 32; ++i) out[(size_t)(row0 + i) * COUT + t] = acc[i];
}

extern "C" void kernel_launch(void* const* d_in, const int* in_sizes, int n_in,
                              void* d_out, int out_size, void* d_ws, size_t ws_size,
                              hipStream_t stream) {
    (void)in_sizes; (void)n_in; (void)out_size; (void)ws_size;
    const float* x = (const float*)d_in[0];
    const float* tab = (const float*)d_in[1];
    const float* W = (const float*)d_in[2];
    const float* b = (const float*)d_in[3];
    float* out = (float*)d_out;

    char* ws = (char*)d_ws;
    float* sq = (float*)ws;                                       // 64 KB
    unsigned short* cand = (unsigned short*)(sq + NPTS);          // N*24 u16 = 768 KB
    unsigned short* nbr = cand + (size_t)NPTS * NHALF * NCAND;    // N*9 u16 = 288 KB
    // total 1.09 MiB < 1.375 MiB proven-safe (round 8)

    sqnp_kernel<<<NPTS / 256, 256, 0, stream>>>(x, sq);
    knn_kernel<<<dim3(NPTS / 64, NHALF), 256, 0, stream>>>(x, sq, cand);
    refine_np_kernel<<<NPTS / 256, 256, 0, stream>>>(x, sq, cand, nbr);
    out_kernel<<<NPTS / 32, 256, 0, stream>>>(x, tab, W, b, nbr, out);
}

// Round 14
// 1135.206 us; speedup vs baseline: 11.9585x; 1.0873x over previous
//
#include <hip/hip_runtime.h>

#define NPTS 16384
#define CH 128
#define KNN 9
#define NCAND 12          // per column-half
#define NHALF 2           // column splits
#define COUT 256

typedef __attribute__((ext_vector_type(8))) short bf16x8;
typedef __attribute__((ext_vector_type(4))) float f32x4;

// Workspace budget: proven safe at 1.375 MiB (round 8); 2.125 MiB corrupted
// harness memory (round 10). d_ws layout = 1.09 MiB. DO NOT GROW.
// Large scratch (xhi/xlo, 8 MB) lives in d_out (16 MB fp32) — legal: harness
// re-poisons d_out each replay, we recompute every launch, out_kernel
// overwrites all of it last.

// Split f -> bf16 hi + bf16 lo (RNE). h/l are packed pairs (x0 low, x1 high).
// hi subtraction is exact in fp32; dropped lo*lo term ~2^-18 rel -> distance
// error ~1e-4 abs, far below the per-half rank-12 candidate margin (~2.7).
__device__ __forceinline__ void bfsplit2(float x0, float x1, unsigned& h, unsigned& l) {
    unsigned u0 = __float_as_uint(x0), u1 = __float_as_uint(x1);
    unsigned r0 = (u0 + 0x7fffu + ((u0 >> 16) & 1u)) & 0xffff0000u;
    unsigned r1 = (u1 + 0x7fffu + ((u1 >> 16) & 1u)) & 0xffff0000u;
    float lo0 = x0 - __uint_as_float(r0);
    float lo1 = x1 - __uint_as_float(r1);
    unsigned v0 = __float_as_uint(lo0), v1 = __float_as_uint(lo1);
    unsigned s0 = (v0 + 0x7fffu + ((v0 >> 16) & 1u));
    unsigned s1 = (v1 + 0x7fffu + ((v1 >> 16) & 1u));
    h = (r0 >> 16) | r1;
    l = (s0 >> 16) | (s1 & 0xffff0000u);
}

// ---- Register-guaranteed top-k lists: named scalars only (no arrays!). ----
// LLVM SROA runs before loop unrolling, so loop-indexed private arrays stay in
// scratch (round 6/7: 5.4 GB scratch writes, VALUBusy 7%).
struct TopL {
    float l0,l1,l2,l3,l4,l5,l6,l7,l8,l9,la,lb;
    int   m0,m1,m2,m3,m4,m5,m6,m7,m8,m9,ma,mb;
};
struct Top9 {
    float l0,l1,l2,l3,l4,l5,l6,l7,l8;
    int   m0,m1,m2,m3,m4,m5,m6,m7,m8;
};

__device__ __forceinline__ bool lexlt(float d, int g, float L, int M) {
    return d < L || (d == L && g < M);
}

__device__ __forceinline__ void ins12(TopL& T, float d, int g) {
    if (!lexlt(d, g, T.lb, T.mb)) return;
    bool b0 = lexlt(d,g,T.l0,T.m0);
    bool b1 = lexlt(d,g,T.l1,T.m1);
    bool b2 = lexlt(d,g,T.l2,T.m2);
    bool b3 = lexlt(d,g,T.l3,T.m3);
    bool b4 = lexlt(d,g,T.l4,T.m4);
    bool b5 = lexlt(d,g,T.l5,T.m5);
    bool b6 = lexlt(d,g,T.l6,T.m6);
    bool b7 = lexlt(d,g,T.l7,T.m7);
    bool b8 = lexlt(d,g,T.l8,T.m8);
    bool b9 = lexlt(d,g,T.l9,T.m9);
    bool ba = lexlt(d,g,T.la,T.ma);
    T.lb = ba ? T.la : d;               T.mb = ba ? T.ma : g;
    T.la = b9 ? T.l9 : (ba ? d : T.la); T.ma = b9 ? T.m9 : (ba ? g : T.ma);
    T.l9 = b8 ? T.l8 : (b9 ? d : T.l9); T.m9 = b8 ? T.m8 : (b9 ? g : T.m9);
    T.l8 = b7 ? T.l7 : (b8 ? d : T.l8); T.m8 = b7 ? T.m7 : (b8 ? g : T.m8);
    T.l7 = b6 ? T.l6 : (b7 ? d : T.l7); T.m7 = b6 ? T.m6 : (b7 ? g : T.m7);
    T.l6 = b5 ? T.l5 : (b6 ? d : T.l6); T.m6 = b5 ? T.m5 : (b6 ? g : T.m6);
    T.l5 = b4 ? T.l4 : (b5 ? d : T.l5); T.m5 = b4 ? T.m4 : (b5 ? g : T.m5);
    T.l4 = b3 ? T.l3 : (b4 ? d : T.l4); T.m4 = b3 ? T.m3 : (b4 ? g : T.m4);
    T.l3 = b2 ? T.l2 : (b3 ? d : T.l3); T.m3 = b2 ? T.m2 : (b3 ? g : T.m3);
    T.l2 = b1 ? T.l1 : (b2 ? d : T.l2); T.m2 = b1 ? T.m1 : (b2 ? g : T.m2);
    T.l1 = b0 ? T.l0 : (b1 ? d : T.l1); T.m1 = b0 ? T.m0 : (b1 ? g : T.m1);
    T.l0 = b0 ? d : T.l0;               T.m0 = b0 ? g : T.m0;
}

__device__ __forceinline__ void ins9(Top9& T, float d, int g) {
    if (!lexlt(d, g, T.l8, T.m8)) return;
    bool b0 = lexlt(d,g,T.l0,T.m0);
    bool b1 = lexlt(d,g,T.l1,T.m1);
    bool b2 = lexlt(d,g,T.l2,T.m2);
    bool b3 = lexlt(d,g,T.l3,T.m3);
    bool b4 = lexlt(d,g,T.l4,T.m4);
    bool b5 = lexlt(d,g,T.l5,T.m5);
    bool b6 = lexlt(d,g,T.l6,T.m6);
    bool b7 = lexlt(d,g,T.l7,T.m7);
    T.l8 = b7 ? T.l7 : d;               T.m8 = b7 ? T.m7 : g;
    T.l7 = b6 ? T.l6 : (b7 ? d : T.l7); T.m7 = b6 ? T.m6 : (b7 ? g : T.m7);
    T.l6 = b5 ? T.l5 : (b6 ? d : T.l6); T.m6 = b5 ? T.m5 : (b6 ? g : T.m6);
    T.l5 = b4 ? T.l4 : (b5 ? d : T.l5); T.m5 = b4 ? T.m4 : (b5 ? g : T.m5);
    T.l4 = b3 ? T.l3 : (b4 ? d : T.l4); T.m4 = b3 ? T.m3 : (b4 ? g : T.m4);
    T.l3 = b2 ? T.l2 : (b3 ? d : T.l3); T.m3 = b2 ? T.m2 : (b3 ? g : T.m3);
    T.l2 = b1 ? T.l1 : (b2 ? d : T.l2); T.m2 = b1 ? T.m1 : (b2 ? g : T.m2);
    T.l1 = b0 ? T.l0 : (b1 ? d : T.l1); T.m1 = b0 ? T.m0 : (b1 ? g : T.m1);
    T.l0 = b0 ? d : T.l0;               T.m0 = b0 ? g : T.m0;
}

__device__ __forceinline__ void merge_shfl(TopL& T, int mask) {
    TopL o;
    o.l0=__shfl_xor(T.l0,mask); o.m0=__shfl_xor(T.m0,mask);
    o.l1=__shfl_xor(T.l1,mask); o.m1=__shfl_xor(T.m1,mask);
    o.l2=__shfl_xor(T.l2,mask); o.m2=__shfl_xor(T.m2,mask);
    o.l3=__shfl_xor(T.l3,mask); o.m3=__shfl_xor(T.m3,mask);
    o.l4=__shfl_xor(T.l4,mask); o.m4=__shfl_xor(T.m4,mask);
    o.l5=__shfl_xor(T.l5,mask); o.m5=__shfl_xor(T.m5,mask);
    o.l6=__shfl_xor(T.l6,mask); o.m6=__shfl_xor(T.m6,mask);
    o.l7=__shfl_xor(T.l7,mask); o.m7=__shfl_xor(T.m7,mask);
    o.l8=__shfl_xor(T.l8,mask); o.m8=__shfl_xor(T.m8,mask);
    o.l9=__shfl_xor(T.l9,mask); o.m9=__shfl_xor(T.m9,mask);
    o.la=__shfl_xor(T.la,mask); o.ma=__shfl_xor(T.ma,mask);
    o.lb=__shfl_xor(T.lb,mask); o.mb=__shfl_xor(T.mb,mask);
    ins12(T,o.l0,o.m0); ins12(T,o.l1,o.m1); ins12(T,o.l2,o.m2);
    ins12(T,o.l3,o.m3); ins12(T,o.l4,o.m4); ins12(T,o.l5,o.m5);
    ins12(T,o.l6,o.m6); ins12(T,o.l7,o.m7); ins12(T,o.l8,o.m8);
    ins12(T,o.l9,o.m9); ins12(T,o.la,o.ma); ins12(T,o.lb,o.mb);
}

// ---------------- Kernel 1: numpy pairwise_sum replica of np.sum(x*x, -1) ----------------
// DO NOT TOUCH: this exact rounding order makes selection match the reference
// bit-for-bit (round 6, absmax 0.0).
__global__ __launch_bounds__(256) void sqnp_kernel(const float* __restrict__ x,
                                                   float* __restrict__ sq) {
    const int i = blockIdx.x * 256 + threadIdx.x;
    const float4* row4 = (const float4*)(x + (size_t)i * CH);
    float r[8];
    {
        float4 a = row4[0], b = row4[1];
        r[0] = __fmul_rn(a.x, a.x); r[1] = __fmul_rn(a.y, a.y);
        r[2] = __fmul_rn(a.z, a.z); r[3] = __fmul_rn(a.w, a.w);
        r[4] = __fmul_rn(b.x, b.x); r[5] = __fmul_rn(b.y, b.y);
        r[6] = __fmul_rn(b.z, b.z); r[7] = __fmul_rn(b.w, b.w);
    }
#pragma unroll
    for (int g = 1; g < 16; ++g) {
        float4 a = row4[2 * g], b = row4[2 * g + 1];
        r[0] = __fadd_rn(r[0], __fmul_rn(a.x, a.x));
        r[1] = __fadd_rn(r[1], __fmul_rn(a.y, a.y));
        r[2] = __fadd_rn(r[2], __fmul_rn(a.z, a.z));
        r[3] = __fadd_rn(r[3], __fmul_rn(a.w, a.w));
        r[4] = __fadd_rn(r[4], __fmul_rn(b.x, b.x));
        r[5] = __fadd_rn(r[5], __fmul_rn(b.y, b.y));
        r[6] = __fadd_rn(r[6], __fmul_rn(b.z, b.z));
        r[7] = __fadd_rn(r[7], __fmul_rn(b.w, b.w));
    }
    float t0 = __fadd_rn(__fadd_rn(r[0], r[1]), __fadd_rn(r[2], r[3]));
    float t1 = __fadd_rn(__fadd_rn(r[4], r[5]), __fadd_rn(r[6], r[7]));
    sq[i] = __fadd_rn(t0, t1);
}

// ---------- Kernel 1.5: one-shot fp32 -> bf16 hi/lo split, swizzled tile layout -------
// Round-13 counters: VALUBusy 48% — each point was re-split 256x inside knn's
// K-loop. Split ONCE here; knn staging becomes a pure 16B copy.
// Layout: xhi[r*128 + (s^(r&15))*8 + j] = hi(x[r][s*8+j]) — identical to the
// LDS physical layout, so staging copies physical slots 1:1.
__global__ __launch_bounds__(256) void split_kernel(const float* __restrict__ x,
                                                    short* __restrict__ xhi,
                                                    short* __restrict__ xlo) {
    const int P = blockIdx.x * 256 + threadIdx.x;  // (row, slot): N*16 tasks
    const int r = P >> 4;
    const int s = P & 15;
    const int phys = s ^ (r & 15);
    const float4* src = (const float4*)(x + (size_t)r * CH) + s * 2;
    float4 f0 = src[0], f1 = src[1];
    uint4 h, l;
    bfsplit2(f0.x, f0.y, h.x, l.x);
    bfsplit2(f0.z, f0.w, h.y, l.y);
    bfsplit2(f1.x, f1.y, h.z, l.z);
    bfsplit2(f1.z, f1.w, h.w, l.w);
    *(uint4*)&xhi[(size_t)r * 128 + phys * 8] = h;
    *(uint4*)&xlo[(size_t)r * 128 + phys * 8] = l;
}

// ------------- Kernel 2: split-bf16 MFMA distance-GEMM + per-half top-12 --------------
// dot = hi*hi + hi*lo + lo*hi via mfma_f32_16x16x32_bf16 (3 MFMA per k-chunk).
// Staging = straight uint4 copy from pre-split global (see split_kernel).
// LDS 80 KiB -> 2 blk/CU. Fragment layouts (m89/m120 verified).
__global__ __launch_bounds__(256, 2) void knn_kernel(const short* __restrict__ xhi,
                                                     const short* __restrict__ xlo,
                                                     const float* __restrict__ sq,
                                                     unsigned short* __restrict__ cand) {
    __shared__ short Ahi[64 * 128];
    __shared__ short Alo[64 * 128];
    __shared__ short Bhi[64 * 128];
    __shared__ short Blo[64 * 128];
    __shared__ float Dist[64 * 64];
    const int t = threadIdx.x;
    const int row0 = blockIdx.x * 64;
    const int half = blockIdx.y;
    const int ctbeg = half * (NPTS / NHALF);
    const int ctend = ctbeg + NPTS / NHALF;

    // ---- stage A (query rows) once: pure copy, layout already swizzled ----
#pragma unroll
    for (int it = 0; it < 4; ++it) {
        const int P = t + it * 256;  // physical (row, slot)
        *(uint4*)&Ahi[P * 8] = *(const uint4*)&xhi[(size_t)row0 * 128 + P * 8];
        *(uint4*)&Alo[P * 8] = *(const uint4*)&xlo[(size_t)row0 * 128 + P * 8];
    }

    const int lane = t & 63;
    const int w = t >> 6;          // wave id: rows [16w, 16w+16)
    const int m = lane & 15;
    const int quad = lane >> 4;
    const float4 sqr4 = *(const float4*)&sq[row0 + 16 * w + quad * 4];

    TopL T;
    T.l0=T.l1=T.l2=T.l3=T.l4=T.l5=T.l6=T.l7=T.l8=T.l9=T.la=T.lb = __builtin_inff();
    T.m0=T.m1=T.m2=T.m3=T.m4=T.m5=T.m6=T.m7=T.m8=T.m9=T.ma=T.mb = 0x7fffffff;

    const int srow = t >> 2;       // selection-phase row (0..63)
    const int sq4 = t & 3;         // selection-phase column quarter
    const int srowg = row0 + srow;

    for (int ct = ctbeg; ct < ctend; ct += 64) {
        // ---- stage B tile: pure copy ----
#pragma unroll
        for (int it = 0; it < 4; ++it) {
            const int P = t + it * 256;
            *(uint4*)&Bhi[P * 8] = *(const uint4*)&xhi[(size_t)ct * 128 + P * 8];
            *(uint4*)&Blo[P * 8] = *(const uint4*)&xlo[(size_t)ct * 128 + P * 8];
        }
        __syncthreads();

        const float sqc0 = sq[ct + 0  + m];
        const float sqc1 = sq[ct + 16 + m];
        const float sqc2 = sq[ct + 32 + m];
        const float sqc3 = sq[ct + 48 + m];

        f32x4 acc0 = {0.f,0.f,0.f,0.f};
        f32x4 acc1 = {0.f,0.f,0.f,0.f};
        f32x4 acc2 = {0.f,0.f,0.f,0.f};
        f32x4 acc3 = {0.f,0.f,0.f,0.f};

#pragma unroll
        for (int kc = 0; kc < 4; ++kc) {
            const int ks = ((kc * 4 + quad) ^ m) * 8;
            const int ar = (16 * w + m) * 128 + ks;
            bf16x8 ah = *(const bf16x8*)&Ahi[ar];
            bf16x8 al = *(const bf16x8*)&Alo[ar];
            bf16x8 bh0 = *(const bf16x8*)&Bhi[(0  + m) * 128 + ks];
            bf16x8 bl0 = *(const bf16x8*)&Blo[(0  + m) * 128 + ks];
            bf16x8 bh1 = *(const bf16x8*)&Bhi[(16 + m) * 128 + ks];
            bf16x8 bl1 = *(const bf16x8*)&Blo[(16 + m) * 128 + ks];
            bf16x8 bh2 = *(const bf16x8*)&Bhi[(32 + m) * 128 + ks];
            bf16x8 bl2 = *(const bf16x8*)&Blo[(32 + m) * 128 + ks];
            bf16x8 bh3 = *(const bf16x8*)&Bhi[(48 + m) * 128 + ks];
            bf16x8 bl3 = *(const bf16x8*)&Blo[(48 + m) * 128 + ks];
            acc0 = __builtin_amdgcn_mfma_f32_16x16x32_bf16(ah, bh0, acc0, 0, 0, 0);
            acc0 = __builtin_amdgcn_mfma_f32_16x16x32_bf16(ah, bl0, acc0, 0, 0, 0);
            acc0 = __builtin_amdgcn_mfma_f32_16x16x32_bf16(al, bh0, acc0, 0, 0, 0);
            acc1 = __builtin_amdgcn_mfma_f32_16x16x32_bf16(ah, bh1, acc1, 0, 0, 0);
            acc1 = __builtin_amdgcn_mfma_f32_16x16x32_bf16(ah, bl1, acc1, 0, 0, 0);
            acc1 = __builtin_amdgcn_mfma_f32_16x16x32_bf16(al, bh1, acc1, 0, 0, 0);
            acc2 = __builtin_amdgcn_mfma_f32_16x16x32_bf16(ah, bh2, acc2, 0, 0, 0);
            acc2 = __builtin_amdgcn_mfma_f32_16x16x32_bf16(ah, bl2, acc2, 0, 0, 0);
            acc2 = __builtin_amdgcn_mfma_f32_16x16x32_bf16(al, bh2, acc2, 0, 0, 0);
            acc3 = __builtin_amdgcn_mfma_f32_16x16x32_bf16(ah, bh3, acc3, 0, 0, 0);
            acc3 = __builtin_amdgcn_mfma_f32_16x16x32_bf16(ah, bl3, acc3, 0, 0, 0);
            acc3 = __builtin_amdgcn_mfma_f32_16x16x32_bf16(al, bh3, acc3, 0, 0, 0);
        }

        // D (col=lane&15, row=quad*4+reg) -> Dist LDS, physical col = col ^ row
#pragma unroll
        for (int reg = 0; reg < 4; ++reg) {
            const int row = 16 * w + quad * 4 + reg;
            const float sqr_r = (reg == 0) ? sqr4.x : (reg == 1) ? sqr4.y
                              : (reg == 2) ? sqr4.z : sqr4.w;
            const int c0 = 0  + m;
            const int c1 = 16 + m;
            const int c2 = 32 + m;
            const int c3 = 48 + m;
            Dist[row * 64 + (c0 ^ row)] = sqr_r + sqc0 - 2.f * acc0[reg];
            Dist[row * 64 + (c1 ^ row)] = sqr_r + sqc1 - 2.f * acc1[reg];
            Dist[row * 64 + (c2 ^ row)] = sqr_r + sqc2 - 2.f * acc2[reg];
            Dist[row * 64 + (c3 ^ row)] = sqr_r + sqc3 - 2.f * acc3[reg];
        }
        __syncthreads();

        // selection scan: 16 candidates from this tile for row srow
#pragma unroll
        for (int k = 0; k < 16; ++k) {
            const int col = sq4 * 16 + k;
            const float d = Dist[srow * 64 + (col ^ srow)];
            const int cg = ct + col;
            if (cg != srowg) ins12(T, d, cg);
        }
    }

    // merge the 4 partial lists per row (lanes t^1, t^2 share srow)
    merge_shfl(T, 1);
    merge_shfl(T, 2);

    if (sq4 == 0) {
        unsigned short* cp_out = cand + (size_t)srowg * (NHALF * NCAND) + half * NCAND;
        cp_out[0]=(unsigned short)T.m0; cp_out[1]=(unsigned short)T.m1;
        cp_out[2]=(unsigned short)T.m2; cp_out[3]=(unsigned short)T.m3;
        cp_out[4]=(unsigned short)T.m4; cp_out[5]=(unsigned short)T.m5;
        cp_out[6]=(unsigned short)T.m6; cp_out[7]=(unsigned short)T.m7;
        cp_out[8]=(unsigned short)T.m8; cp_out[9]=(unsigned short)T.m9;
        cp_out[10]=(unsigned short)T.ma; cp_out[11]=(unsigned short)T.mb;
    }
}

// ---------------- Kernel 2.5: numpy-fp32-replica re-rank of 24 candidates ----------------
// dot: BLAS sgemm per-element rounding = ONE accumulator, sequential ascending-k FMA.
// d  : fl( fl(sq_i + sq_j) - fl(2*dot) ).
// DO NOT TOUCH the rounding order — verified exact vs reference (round 6, absmax 0.0).
__global__ __launch_bounds__(256) void refine_np_kernel(const float* __restrict__ x,
                                                        const float* __restrict__ sq,
                                                        const unsigned short* __restrict__ cand,
                                                        unsigned short* __restrict__ nbr) {
    const int i = blockIdx.x * 256 + threadIdx.x;
    const float4* X4 = (const float4*)x;
    const float sqi = sq[i];

    Top9 T;
    T.l0=T.l1=T.l2=T.l3=T.l4=T.l5=T.l6=T.l7=T.l8 = __builtin_inff();
    T.m0=T.m1=T.m2=T.m3=T.m4=T.m5=T.m6=T.m7=T.m8 = 0x7fffffff;

#pragma unroll
    for (int b = 0; b < NHALF; ++b) {
        int ci[NCAND];
#pragma unroll
        for (int m = 0; m < NCAND; ++m)
            ci[m] = (int)cand[i * (NHALF * NCAND) + b * NCAND + m];
        float dot[NCAND];
#pragma unroll
        for (int m = 0; m < NCAND; ++m) dot[m] = 0.f;
#pragma unroll 4
        for (int c4 = 0; c4 < 32; ++c4) {
            float4 xv = X4[(size_t)i * 32 + c4];
#pragma unroll
            for (int m = 0; m < NCAND; ++m) {
                float4 nv = X4[(size_t)ci[m] * 32 + c4];
                float a = dot[m];
                a = __builtin_fmaf(xv.x, nv.x, a);
                a = __builtin_fmaf(xv.y, nv.y, a);
                a = __builtin_fmaf(xv.z, nv.z, a);
                a = __builtin_fmaf(xv.w, nv.w, a);
                dot[m] = a;
            }
        }
#pragma unroll
        for (int m = 0; m < NCAND; ++m) {
            float s = __fadd_rn(sqi, sq[ci[m]]);
            float d = __fsub_rn(s, __fmul_rn(2.0f, dot[m]));
            ins9(T, d, ci[m]);
        }
    }

    unsigned short* np = nbr + (size_t)i * KNN;
    np[0]=(unsigned short)T.m0; np[1]=(unsigned short)T.m1; np[2]=(unsigned short)T.m2;
    np[3]=(unsigned short)T.m3; np[4]=(unsigned short)T.m4; np[5]=(unsigned short)T.m5;
    np[6]=(unsigned short)T.m6; np[7]=(unsigned short)T.m7; np[8]=(unsigned short)T.m8;
}

// ---------------- Kernel 3: rel-pos add + max-relative + concat-GEMM ----------------
__global__ __launch_bounds__(256, 2) void out_kernel(const float* __restrict__ x,
                                                     const float* __restrict__ tab,
                                                     const float* __restrict__ W,
                                                     const float* __restrict__ bias,
                                                     const unsigned short* __restrict__ nbr,
                                                     float* __restrict__ out) {
    __shared__ float cat[32][260];
    const int t = threadIdx.x;
    const int row0 = blockIdx.x * 32;
    {
        const int row = t >> 3;
        const int q = t & 7;
        const int i = row0 + row;
        const int rel_i = (i >> 7) - (i & 127) + 127;
        int nb[KNN], reln[KNN];
#pragma unroll
        for (int j = 0; j < KNN; ++j) {
            nb[j] = (int)nbr[i * KNN + j];
            reln[j] = (nb[j] >> 7) - (nb[j] & 127) + 127;
        }
        const float4* X4 = (const float4*)x;
        const float4* T4 = (const float4*)tab;
#pragma unroll
        for (int cc = 0; cc < 4; ++cc) {
            const int c4 = q * 4 + cc;
            float4 xv = X4[i * 32 + c4];
            float4 tv = T4[rel_i * 32 + c4];
            float4 xi;
            xi.x = xv.x + tv.x; xi.y = xv.y + tv.y; xi.z = xv.z + tv.z; xi.w = xv.w + tv.w;
            const float ninf = -__builtin_inff();
            float4 mx = {ninf, ninf, ninf, ninf};
#pragma unroll
            for (int j = 0; j < KNN; ++j) {
                float4 nv = X4[nb[j] * 32 + c4];
                float4 ntv = T4[reln[j] * 32 + c4];
                mx.x = fmaxf(mx.x, nv.x + ntv.x - xi.x);
                mx.y = fmaxf(mx.y, nv.y + ntv.y - xi.y);
                mx.z = fmaxf(mx.z, nv.z + ntv.z - xi.z);
                mx.w = fmaxf(mx.w, nv.w + ntv.w - xi.w);
            }
            *(float4*)&cat[row][c4 * 4] = xi;
            *(float4*)&cat[row][CH + c4 * 4] = mx;
        }
    }
    __syncthreads();

    float acc[32];
    const float bo = bias[t];
#pragma unroll
    for (int i = 0; i < 32; ++i) acc[i] = bo;
#pragma unroll 2
    for (int c0 = 0; c0 < 2 * CH; c0 += 4) {
        const float w0 = W[(c0 + 0) * COUT + t];
        const float w1 = W[(c0 + 1) * COUT + t];
        const float w2 = W[(c0 + 2) * COUT + t];
        const float w3 = W[(c0 + 3) * COUT + t];
#pragma unroll
        for (int i = 0; i < 32; ++i) {
            const float4 cv = *(const float4*)&cat[i][c0];
            acc[i] = fmaf(cv.x, w0, acc[i]);
            acc[i] = fmaf(cv.y, w1, acc[i]);
            acc[i] = fmaf(cv.z, w2, acc[i]);
            acc[i] = fmaf(cv.w, w3, acc[i]);
        }
    }
#pragma unroll
    for (int i = 0; i < 32; ++i) out[(size_t)(row0 + i) * COUT + t] = acc[i];
}

extern "C" void kernel_launch(void* const* d_in, const int* in_sizes, int n_in,
                              void* d_out, int out_size, void* d_ws, size_t ws_size,
                              hipStream_t stream) {
    (void)in_sizes; (void)n_in; (void)out_size; (void)ws_size;
    const float* x = (const float*)d_in[0];
    const float* tab = (const float*)d_in[1];
    const float* W = (const float*)d_in[2];
    const float* b = (const float*)d_in[3];
    float* out = (float*)d_out;

    char* ws = (char*)d_ws;
    float* sq = (float*)ws;                                       // 64 KB
    unsigned short* cand = (unsigned short*)(sq + NPTS);          // N*24 u16 = 768 KB
    unsigned short* nbr = cand + (size_t)NPTS * NHALF * NCAND;    // N*9 u16 = 288 KB
    // d_ws total 1.09 MiB < 1.375 MiB proven-safe (round 8)

    // xhi/xlo scratch in d_out (16 MB): 4 MB + 4 MB, overwritten by out_kernel.
    short* xhi = (short*)d_out;
    short* xlo = xhi + (size_t)NPTS * CH;

    sqnp_kernel<<<NPTS / 256, 256, 0, stream>>>(x, sq);
    split_kernel<<<NPTS * 16 / 256, 256, 0, stream>>>(x, xhi, xlo);
    knn_kernel<<<dim3(NPTS / 64, NHALF), 256, 0, stream>>>(xhi, xlo, sq, cand);
    refine_np_kernel<<<NPTS / 256, 256, 0, stream>>>(x, sq, cand, nbr);
    out_kernel<<<NPTS / 32, 256, 0, stream>>>(x, tab, W, b, nbr, out);
}